// Round 4
// baseline (532.121 us; speedup 1.0000x reference)
//
#include <hip/hip_runtime.h>

#define L_SZ 200
#define RB 8
#define ELEMS 4
#define HS_STRIDE 72   // bf16 elems per H row: 64 + 8 pad (144 B, 16B-aligned)

typedef __attribute__((ext_vector_type(8))) short short8;   // 8 bf16 = 4 VGPRs (MFMA A/B frag)
typedef __attribute__((ext_vector_type(4))) float floatx4;  // MFMA C/D frag

__device__ __forceinline__ unsigned short f2bf(float f) {
    unsigned int u = __float_as_uint(f);
    unsigned int r = (u + 0x7fffu + ((u >> 16) & 1u)) >> 16;
    return (unsigned short)r;
}
__device__ __forceinline__ float bf2f(unsigned short h) {
    return __uint_as_float(((unsigned int)h) << 16);
}
__device__ __forceinline__ float wave_sum64(float v) {
    #pragma unroll
    for (int m = 1; m <= 32; m <<= 1) v += __shfl_xor(v, m, 64);
    return v;
}
__device__ __forceinline__ float wave_max64(float v) {
    #pragma unroll
    for (int m = 1; m <= 32; m <<= 1) v = fmaxf(v, __shfl_xor(v, m, 64));
    return v;
}
__device__ __forceinline__ unsigned int pk2(float a, float b) {
    return ((unsigned int)f2bf(b) << 16) | (unsigned int)f2bf(a);
}
// LDS-only barrier: does NOT drain vmcnt, so cross-element global prefetch
// loads stay in flight across it. All intra-block communication is LDS.
__device__ __forceinline__ void bar_lds() {
    asm volatile("s_waitcnt lgkmcnt(0)" ::: "memory");
    __builtin_amdgcn_s_barrier();
    asm volatile("" ::: "memory");
}

// ---------------------------------------------------------------------------
// prep_kernel (65 blocks, ~2-3 us total):
//   block 0      : T1t[j][k] = aW0[k][j] + aW0[192+k][j]  (transpose via padded LDS)
//                  T2t[j][k] = aW0[128+k][j]
//                  PW1 frag-packed bf16 of aW1
//   blocks 1..64 : cb_ws for 64 batch rows each:
//                  cb[b][j] = ab0[j] + sum_k iemb_b[k]*(aW0[64+k][j]-aW0[192+k][j])
//                  T3 + 64 item rows staged in LDS; serial k-chain preserved.
// ---------------------------------------------------------------------------
__global__ __launch_bounds__(256) void prep_kernel(
    const int* __restrict__ item_id, const float* __restrict__ item_W,
    const float* __restrict__ aW0, const float* __restrict__ ab0,
    const float* __restrict__ aW1,
    float* __restrict__ T1t, float* __restrict__ T2t,
    unsigned short* __restrict__ PW1, float* __restrict__ cb_ws)
{
    __shared__ float shbuf[3 * 64 * 65];   // 49,920 B
    const int tid = threadIdx.x;
    if (blockIdx.x == 0) {
        #pragma unroll
        for (int t = 0; t < 3; ++t) {
            const int r0 = (t == 0) ? 0 : (t == 1) ? 128 : 192;
            for (int u = tid; u < 1024; u += 256) {          // 64 rows x 16 float4
                int k = u >> 4, c4 = u & 15;
                float4 v = *(const float4*)(aW0 + (r0 + k) * 64 + c4 * 4);
                float* dst = shbuf + t * 4160 + k * 65 + c4 * 4;
                dst[0] = v.x; dst[1] = v.y; dst[2] = v.z; dst[3] = v.w;
            }
        }
        __syncthreads();
        for (int u = tid; u < 4096; u += 256) {
            int j = u >> 6, k = u & 63;
            T1t[u] = shbuf[k * 65 + j] + shbuf[2 * 4160 + k * 65 + j];
            T2t[u] = shbuf[4160 + k * 65 + j];
        }
        for (int u = tid; u < 2048; u += 256) {
            int i = u & 7, lane = (u >> 3) & 63, f = u >> 9;
            int nt = f >> 1, ks = f & 1;
            int k = ks * 32 + (lane >> 4) * 8 + i;
            int n = nt * 16 + (lane & 15);
            PW1[u] = f2bf(aW1[k * 32 + n]);
        }
    } else {
        float* T3 = shbuf;                 // [64][65]
        float* IE = shbuf + 64 * 65;       // [64][64]
        const int B0 = (blockIdx.x - 1) * 64;
        for (int u = tid; u < 4096; u += 256) {
            int k = u >> 6, j = u & 63;
            T3[k * 65 + j] = aW0[(64 + k) * 64 + j] - aW0[(192 + k) * 64 + j];
        }
        for (int u = tid; u < 4096; u += 256) {
            int r = u >> 6, j = u & 63;
            IE[r * 64 + j] = item_W[(size_t)item_id[B0 + r] * 64 + j];
        }
        __syncthreads();
        const int j = tid & 63, rg = tid >> 6;
        for (int pass = 0; pass < 16; ++pass) {
            int bl = rg * 16 + pass;
            float acc = ab0[j];
            #pragma unroll 8
            for (int k = 0; k < 64; ++k)
                acc = fmaf(IE[bl * 64 + k], T3[k * 65 + j], acc);
            cb_ws[(size_t)(B0 + bl) * 64 + j] = acc;
        }
    }
}

// ---------------------------------------------------------------------------
// attn_kernel: 1024 blocks (4 blocks/CU, one round), ELEMS=4 batch elements
// per block, software-pipelined:
//   while element e computes (MFMA/softmax/pooling), element e+1's 14x16B
//   gathers sit in flight in registers. All barriers are LDS-only (bar_lds)
//   so the prefetch is never drained by vmcnt(0).
// Per element: pack -> WeT build -> bar -> bW hoist -> bar -> [issue e+1
// gathers] -> main MFMA loop -> softmax -> pooling -> bar -> write.
// LDS 39,424 B -> 4 blocks/CU. __launch_bounds__(256,4) pins VGPR <= 128.
// ---------------------------------------------------------------------------
__global__ __launch_bounds__(256, 4) void attn_kernel(
    const int* __restrict__ item_id, const int* __restrict__ hist_seq,
    const float* __restrict__ item_W, const float* __restrict__ hist_W,
    const float* __restrict__ T1t, const float* __restrict__ T2t,
    const unsigned short* __restrict__ PW1, const float* __restrict__ cb_ws,
    const float* __restrict__ ab1, const float* __restrict__ aW2,
    const float* __restrict__ ab2, float* __restrict__ pooled_ws)
{
    __shared__ __align__(16) unsigned char smem[39424];
    unsigned short* Hs  = (unsigned short*)(smem);           // 200 x 72 bf16 = 28800 B
    unsigned short* BB  = (unsigned short*)(smem + 28800);   // 8192 B: WeT -> scr -> pools
    int*   seqA   = (int*)(smem + 36992);                    // 200 i32
    int*   seqB   = (int*)(smem + 37792);                    // 200 i32
    float* scores = (float*)(smem + 38592);                  // 200 f32
    float* red    = (float*)(smem + 39392);                  // 8 f32

    const int tid  = threadIdx.x;
    const int w    = tid >> 6;
    const int lane = tid & 63;
    const int c = lane & 15, q = lane >> 4;
    const int rbase = tid >> 3, c8 = tid & 7;
    const bool extra = tid < 64;
    const int b0 = blockIdx.x * ELEMS;

    // ---- batch-invariant register state ----
    short8 bW1[2][2];
    #pragma unroll
    for (int nt = 0; nt < 2; ++nt)
        #pragma unroll
        for (int ks = 0; ks < 2; ++ks)
            bW1[nt][ks] = *(const short8*)(PW1 + ((nt * 2 + ks) * 64 + lane) * 8);
    float ab1r[2], aw2r[2];
    #pragma unroll
    for (int nt = 0; nt < 2; ++nt) {
        ab1r[nt] = ab1[nt * 16 + c];
        aw2r[nt] = aW2[nt * 16 + c];
    }
    const float ab2s = ab2[0];
    int iid[ELEMS];
    #pragma unroll
    for (int e = 0; e < ELEMS; ++e) iid[e] = item_id[b0 + e];

    // ---- prologue: seq + gathers for element 0 ----
    int* seq_cur = seqA;
    int* seq_nxt = seqB;
    int si[7];
    {
        const int* hq = hist_seq + (size_t)b0 * L_SZ;
        #pragma unroll
        for (int t = 0; t < 6; ++t) si[t] = hq[rbase + t * 32];
        si[6] = hq[extra ? 192 + rbase : 0];
    }
    #pragma unroll
    for (int t = 0; t < 6; ++t) seq_cur[rbase + t * 32] = si[t];
    if (extra) seq_cur[192 + rbase] = si[6];
    float4 f0[7], f1[7];
    #pragma unroll
    for (int t = 0; t < 7; ++t) {
        const float* p = hist_W + (size_t)si[t] * 64 + c8 * 8;
        f0[t] = *(const float4*)p;
        f1[t] = *(const float4*)(p + 4);
    }

    #pragma unroll 1
    for (int e = 0; e < ELEMS; ++e) {
        const int b = b0 + e;
        // ================= PHASE A: pack & per-element setup =================
        // issue seq loads for e+1 first (latency hidden under pack/WeT)
        if (e + 1 < ELEMS) {
            const int* hq = hist_seq + (size_t)(b + 1) * L_SZ;
            #pragma unroll
            for (int t = 0; t < 6; ++t) si[t] = hq[rbase + t * 32];
            si[6] = hq[extra ? 192 + rbase : 0];
        }
        // per-element cb (from prep) -- issued early, used after barriers
        float cbr[4];
        #pragma unroll
        for (int nt = 0; nt < 4; ++nt)
            cbr[nt] = cb_ws[(size_t)b * 64 + nt * 16 + c];

        // pack this element's gathers -> Hs
        #pragma unroll
        for (int t = 0; t < 6; ++t) {
            uint4 pk;
            pk.x = pk2(f0[t].x, f0[t].y); pk.y = pk2(f0[t].z, f0[t].w);
            pk.z = pk2(f1[t].x, f1[t].y); pk.w = pk2(f1[t].z, f1[t].w);
            *(uint4*)(Hs + (rbase + t * 32) * HS_STRIDE + c8 * 8) = pk;
        }
        if (extra) {
            uint4 pk;
            pk.x = pk2(f0[6].x, f0[6].y); pk.y = pk2(f0[6].z, f0[6].w);
            pk.z = pk2(f1[6].x, f1[6].y); pk.w = pk2(f1[6].z, f1[6].w);
            *(uint4*)(Hs + (192 + rbase) * HS_STRIDE + c8 * 8) = pk;
        }

        // WeT build from prepacked tables: bf16(T1 + iemb*T2), swizzled -> BB
        {
            const float* irow = item_W + (size_t)iid[e] * 64;
            const int j0 = tid >> 3;   // 0..31
            float4 em0 = *(const float4*)(irow + c8 * 8);
            float4 em1 = *(const float4*)(irow + c8 * 8 + 4);
            #pragma unroll
            for (int t = 0; t < 2; ++t) {
                int j = j0 + t * 32;
                const float* p1 = T1t + j * 64 + c8 * 8;
                const float* p2 = T2t + j * 64 + c8 * 8;
                float4 a0 = *(const float4*)p1, a1 = *(const float4*)(p1 + 4);
                float4 b0v = *(const float4*)p2, b1v = *(const float4*)(p2 + 4);
                float v[8];
                v[0] = a0.x + em0.x * b0v.x; v[1] = a0.y + em0.y * b0v.y;
                v[2] = a0.z + em0.z * b0v.z; v[3] = a0.w + em0.w * b0v.w;
                v[4] = a1.x + em1.x * b1v.x; v[5] = a1.y + em1.y * b1v.y;
                v[6] = a1.z + em1.z * b1v.z; v[7] = a1.w + em1.w * b1v.w;
                uint4 pk;
                pk.x = pk2(v[0], v[1]); pk.y = pk2(v[2], v[3]);
                pk.z = pk2(v[4], v[5]); pk.w = pk2(v[6], v[7]);
                *(uint4*)(BB + j * 64 + (c8 ^ (j & 7)) * 8) = pk;
            }
        }
        bar_lds();   // #1: Hs + WeT visible

        // hoist bW frags from swizzled WeT
        short8 bW[4][2];
        #pragma unroll
        for (int nt = 0; nt < 4; ++nt)
            #pragma unroll
            for (int ks = 0; ks < 2; ++ks)
                bW[nt][ks] = *(const short8*)(BB + (nt * 16 + c) * 64
                                                 + ((4 * ks + q) ^ (c & 7)) * 8);
        bar_lds();   // #2: BB free for scr

        // ================= PHASE B: prefetch e+1, compute e =================
        if (e + 1 < ELEMS) {
            #pragma unroll
            for (int t = 0; t < 6; ++t) seq_nxt[rbase + t * 32] = si[t];
            if (extra) seq_nxt[192 + rbase] = si[6];
            #pragma unroll
            for (int t = 0; t < 7; ++t) {
                const float* p = hist_W + (size_t)si[t] * 64 + c8 * 8;
                f0[t] = *(const float4*)p;      // in flight through compute
                f1[t] = *(const float4*)(p + 4);
            }
        }

        unsigned short* scrw = BB + w * (16 * 64);
        const floatx4 zf = {0.f, 0.f, 0.f, 0.f};

        // main: per M-tile  layer0 MFMA -> relu -> scr -> layer1 MFMA -> score
        // (tile 12 rows 200..207 read garbage beyond Hs -> independent, masked)
        for (int mt = w; mt < 13; mt += 4) {
            const int rowbase = mt * 16;
            floatx4 acc0[4] = {zf, zf, zf, zf};
            #pragma unroll
            for (int ks = 0; ks < 2; ++ks) {
                short8 a = *(const short8*)(Hs + (rowbase + c) * HS_STRIDE + ks * 32 + q * 8);
                acc0[0] = __builtin_amdgcn_mfma_f32_16x16x32_bf16(a, bW[0][ks], acc0[0], 0, 0, 0);
                acc0[1] = __builtin_amdgcn_mfma_f32_16x16x32_bf16(a, bW[1][ks], acc0[1], 0, 0, 0);
                acc0[2] = __builtin_amdgcn_mfma_f32_16x16x32_bf16(a, bW[2][ks], acc0[2], 0, 0, 0);
                acc0[3] = __builtin_amdgcn_mfma_f32_16x16x32_bf16(a, bW[3][ks], acc0[3], 0, 0, 0);
            }
            #pragma unroll
            for (int nt = 0; nt < 4; ++nt)
                #pragma unroll
                for (int r = 0; r < 4; ++r) {
                    float h = fmaxf(acc0[nt][r] + cbr[nt], 0.f);
                    int row = q * 4 + r;
                    int gp = (2 * nt + (c >> 3)) ^ (row & 7);
                    scrw[row * 64 + gp * 8 + (c & 7)] = f2bf(h);
                }
            floatx4 acc1[2] = {zf, zf};
            #pragma unroll
            for (int ks = 0; ks < 2; ++ks) {
                short8 a1 = *(const short8*)(scrw + c * 64 + ((4 * ks + q) ^ (c & 7)) * 8);
                acc1[0] = __builtin_amdgcn_mfma_f32_16x16x32_bf16(a1, bW1[0][ks], acc1[0], 0, 0, 0);
                acc1[1] = __builtin_amdgcn_mfma_f32_16x16x32_bf16(a1, bW1[1][ks], acc1[1], 0, 0, 0);
            }
            float s[4];
            #pragma unroll
            for (int r = 0; r < 4; ++r)
                s[r] = fmaxf(acc1[0][r] + ab1r[0], 0.f) * aw2r[0]
                     + fmaxf(acc1[1][r] + ab1r[1], 0.f) * aw2r[1];
            #pragma unroll
            for (int m = 1; m <= 8; m <<= 1)
                #pragma unroll
                for (int r = 0; r < 4; ++r) s[r] += __shfl_xor(s[r], m, 64);
            if (c == 0) {
                #pragma unroll
                for (int r = 0; r < 4; ++r) {
                    int l = rowbase + q * 4 + r;
                    if (l < L_SZ)
                        scores[l] = (seq_cur[l] == 0) ? -1.0e9f : (s[r] + ab2s);
                }
            }
        }
        bar_lds();

        // ---- masked softmax over 200 scores ----
        float s0 = (tid < L_SZ) ? scores[tid] : -3.0e38f;
        float mx = wave_max64(s0);
        if (lane == 0) red[w] = mx;
        bar_lds();
        mx = fmaxf(fmaxf(red[0], red[1]), fmaxf(red[2], red[3]));
        float ev = (tid < L_SZ) ? __expf(s0 - mx) : 0.f;
        float sm = wave_sum64(ev);
        if (lane == 0) red[4 + w] = sm;
        bar_lds();
        const float winv = 1.f / ((red[4] + red[5]) + (red[6] + red[7]));
        if (tid < L_SZ) scores[tid] = ev * winv;
        bar_lds();

        // ---- pooled[j] = sum_l w_l * H[l][j] ----
        float* pools = (float*)BB;   // scr dead now
        {
            int g  = (w << 1) | (lane >> 5);
            int jj = lane & 31;
            int l0 = g * 26, l1 = (l0 + 26 < L_SZ) ? l0 + 26 : L_SZ;
            float p0 = 0.f, p1 = 0.f;
            for (int l = l0; l < l1; ++l) {
                float wt = scores[l];
                unsigned int pv = *(const unsigned int*)(Hs + l * HS_STRIDE + jj * 2);
                p0 = fmaf(wt, bf2f((unsigned short)(pv & 0xffffu)), p0);
                p1 = fmaf(wt, bf2f((unsigned short)(pv >> 16)), p1);
            }
            float2 pp = {p0, p1};
            *(float2*)&pools[g * 64 + jj * 2] = pp;
        }
        bar_lds();
        if (tid < 64) {
            float sum = 0.f;
            #pragma unroll
            for (int g = 0; g < 8; ++g) sum += pools[g * 64 + tid];
            pooled_ws[(size_t)b * 64 + tid] = sum;
        }
        bar_lds();   // protect Hs/BB/scores/seq before next element's PHASE A

        int* tp = seq_cur; seq_cur = seq_nxt; seq_nxt = tp;
    }
}

// Main MLP: 244 -> 256 -> 128 -> 1 -> sigmoid. One block per RB=8 rows.
__global__ __launch_bounds__(256) void mlp_kernel(
    const int* __restrict__ user_id, const int* __restrict__ item_id,
    const int* __restrict__ item_cat, const int* __restrict__ item_dur,
    const float* __restrict__ user_dense, const float* __restrict__ item_dense,
    const float* __restrict__ user_W, const float* __restrict__ item_W,
    const float* __restrict__ cat_W, const float* __restrict__ dur_W,
    const float* __restrict__ mW0, const float* __restrict__ mb0,
    const float* __restrict__ mW1, const float* __restrict__ mb1,
    const float* __restrict__ mW2, const float* __restrict__ mb2,
    const float* __restrict__ pooled_ws, float* __restrict__ out)
{
    __shared__ __align__(16) float xT[244][RB];
    __shared__ __align__(16) float h0T[256][RB];
    __shared__ __align__(16) float h1T[128][RB];
    __shared__ __align__(16) float part[128][RB];

    const int tid = threadIdx.x;
    const int b0 = blockIdx.x * RB;

    for (int idx = tid; idx < 244 * RB; idx += 256) {
        int r = idx / 244;
        int c = idx - r * 244;
        int b = b0 + r;
        float v;
        if (c < 64)       v = user_W[(size_t)user_id[b] * 64 + c];
        else if (c < 128) v = item_W[(size_t)item_id[b] * 64 + (c - 64)];
        else if (c < 144) v = cat_W[item_cat[b] * 16 + (c - 128)];
        else if (c < 152) v = dur_W[item_dur[b] * 8 + (c - 144)];
        else if (c < 177) v = user_dense[b * 25 + (c - 152)];
        else if (c < 180) v = item_dense[b * 3 + (c - 177)];
        else              v = pooled_ws[(size_t)b * 64 + (c - 180)];
        xT[c][r] = v;
    }
    __syncthreads();

    {
        float acc[RB];
        const float bias = mb0[tid];
        #pragma unroll
        for (int r = 0; r < RB; ++r) acc[r] = bias;
        #pragma unroll 4
        for (int k = 0; k < 244; ++k) {
            float wk = mW0[k * 256 + tid];
            float4 xa = *(const float4*)&xT[k][0];
            float4 xb = *(const float4*)&xT[k][4];
            acc[0] = fmaf(wk, xa.x, acc[0]);
            acc[1] = fmaf(wk, xa.y, acc[1]);
            acc[2] = fmaf(wk, xa.z, acc[2]);
            acc[3] = fmaf(wk, xa.w, acc[3]);
            acc[4] = fmaf(wk, xb.x, acc[4]);
            acc[5] = fmaf(wk, xb.y, acc[5]);
            acc[6] = fmaf(wk, xb.z, acc[6]);
            acc[7] = fmaf(wk, xb.w, acc[7]);
        }
        #pragma unroll
        for (int r = 0; r < RB; ++r) h0T[tid][r] = fmaxf(acc[r], 0.f);
    }
    __syncthreads();

    const int jj = tid & 127;
    const int half = tid >> 7;
    {
        float acc[RB];
        #pragma unroll
        for (int r = 0; r < RB; ++r) acc[r] = 0.f;
        #pragma unroll 4
        for (int t = 0; t < 128; ++t) {
            int k = half * 128 + t;
            float wk = mW1[k * 128 + jj];
            float4 ha = *(const float4*)&h0T[k][0];
            float4 hb = *(const float4*)&h0T[k][4];
            acc[0] = fmaf(wk, ha.x, acc[0]);
            acc[1] = fmaf(wk, ha.y, acc[1]);
            acc[2] = fmaf(wk, ha.z, acc[2]);
            acc[3] = fmaf(wk, ha.w, acc[3]);
            acc[4] = fmaf(wk, hb.x, acc[4]);
            acc[5] = fmaf(wk, hb.y, acc[5]);
            acc[6] = fmaf(wk, hb.z, acc[6]);
            acc[7] = fmaf(wk, hb.w, acc[7]);
        }
        if (half == 1) {
            #pragma unroll
            for (int r = 0; r < RB; ++r) part[jj][r] = acc[r];
        }
        __syncthreads();
        if (half == 0) {
            const float bias = mb1[jj];
            #pragma unroll
            for (int r = 0; r < RB; ++r)
                h1T[jj][r] = fmaxf(acc[r] + part[jj][r] + bias, 0.f);
        }
    }
    __syncthreads();

    if (tid < RB) {
        const int r = tid;
        float a0 = mb2[0], a1 = 0.f;
        #pragma unroll 8
        for (int k = 0; k < 128; k += 2) {
            a0 = fmaf(h1T[k][r],     mW2[k],     a0);
            a1 = fmaf(h1T[k + 1][r], mW2[k + 1], a1);
        }
        float a = a0 + a1;
        out[b0 + r] = 1.f / (1.f + __expf(-a));
    }
}

extern "C" void kernel_launch(void* const* d_in, const int* in_sizes, int n_in,
                              void* d_out, int out_size, void* d_ws, size_t ws_size,
                              hipStream_t stream) {
    (void)in_sizes; (void)n_in; (void)out_size; (void)ws_size;
    const int*   user_id    = (const int*)d_in[0];
    const int*   item_id    = (const int*)d_in[1];
    const int*   item_cat   = (const int*)d_in[2];
    const int*   item_dur   = (const int*)d_in[3];
    const float* user_dense = (const float*)d_in[4];
    const float* item_dense = (const float*)d_in[5];
    const int*   hist_seq   = (const int*)d_in[6];
    const float* user_W     = (const float*)d_in[7];
    const float* item_W     = (const float*)d_in[8];
    const float* cat_W      = (const float*)d_in[9];
    const float* dur_W      = (const float*)d_in[10];
    const float* hist_W     = (const float*)d_in[11];
    const float* aW0 = (const float*)d_in[12];
    const float* ab0 = (const float*)d_in[13];
    const float* aW1 = (const float*)d_in[14];
    const float* ab1 = (const float*)d_in[15];
    const float* aW2 = (const float*)d_in[16];
    const float* ab2 = (const float*)d_in[17];
    const float* mW0 = (const float*)d_in[18];
    const float* mb0 = (const float*)d_in[19];
    const float* mW1 = (const float*)d_in[20];
    const float* mb1 = (const float*)d_in[21];
    const float* mW2 = (const float*)d_in[22];
    const float* mb2 = (const float*)d_in[23];
    float* out = (float*)d_out;

    // workspace: pooled 1MB | cb 1MB | T1t 16KB | T2t 16KB | PW1 4KB
    char* ws = (char*)d_ws;
    float* pooled_ws = (float*)ws;                               // 4096*64 f32
    float* cb_ws     = (float*)(ws + (1u << 20));                // 4096*64 f32
    float* T1t       = (float*)(ws + (2u << 20));                // 64*64 f32
    float* T2t       = (float*)(ws + (2u << 20) + 16384);        // 64*64 f32
    unsigned short* PW1 = (unsigned short*)(ws + (2u << 20) + 32768); // 2048 bf16

    prep_kernel<<<65, 256, 0, stream>>>(item_id, item_W, aW0, ab0, aW1,
                                        T1t, T2t, PW1, cb_ws);
    attn_kernel<<<4096 / ELEMS, 256, 0, stream>>>(item_id, hist_seq, item_W, hist_W,
                                                  T1t, T2t, PW1, cb_ws,
                                                  ab1, aW2, ab2, pooled_ws);
    mlp_kernel<<<4096 / RB, 256, 0, stream>>>(user_id, item_id, item_cat, item_dur,
                                              user_dense, item_dense,
                                              user_W, item_W, cat_W, dur_W,
                                              mW0, mb0, mW1, mb1, mW2, mb2,
                                              pooled_ws, out);
}

// Round 5
// 398.744 us; speedup vs baseline: 1.3345x; 1.3345x over previous
//
#include <hip/hip_runtime.h>

#define L_SZ 200
#define RB 8
#define HS_STRIDE 72   // bf16 elems per H row: 64 + 8 pad (144 B, 16B-aligned)

typedef __attribute__((ext_vector_type(8))) short short8;   // 8 bf16 = 4 VGPRs (MFMA A/B frag)
typedef __attribute__((ext_vector_type(4))) float floatx4;  // MFMA C/D frag

__device__ __forceinline__ unsigned short f2bf(float f) {
    unsigned int u = __float_as_uint(f);
    unsigned int r = (u + 0x7fffu + ((u >> 16) & 1u)) >> 16;
    return (unsigned short)r;
}
__device__ __forceinline__ float bf2f(unsigned short h) {
    return __uint_as_float(((unsigned int)h) << 16);
}
// HW packed convert: 1 instruction replaces ~10-op RNE emulation (same RNE result).
__device__ __forceinline__ unsigned int pk2(float a, float b) {
    unsigned int r;
    asm("v_cvt_pk_bf16_f32 %0, %1, %2" : "=v"(r) : "v"(a), "v"(b));
    return r;   // low16 = bf16(a), high16 = bf16(b)
}
__device__ __forceinline__ float wave_sum64(float v) {
    #pragma unroll
    for (int m = 1; m <= 32; m <<= 1) v += __shfl_xor(v, m, 64);
    return v;
}
__device__ __forceinline__ float wave_max64(float v) {
    #pragma unroll
    for (int m = 1; m <= 32; m <<= 1) v = fmaxf(v, __shfl_xor(v, m, 64));
    return v;
}
// LDS-only barrier: waits LDS ops but does NOT drain vmcnt -> early-issued
// global loads stay in flight across it. All intra-block comms are via LDS.
__device__ __forceinline__ void bar_lds() {
    asm volatile("s_waitcnt lgkmcnt(0)" ::: "memory");
    __builtin_amdgcn_s_barrier();
    asm volatile("" ::: "memory");
}

// ---------------------------------------------------------------------------
// prep_kernel (65 blocks, cheap):
//   block 0      : T1t[j][k] = aW0[k][j] + aW0[192+k][j]  (transpose via padded LDS)
//                  T2t[j][k] = aW0[128+k][j]
//                  PW1 frag-packed bf16 of aW1
//   blocks 1..64 : cb_ws for 64 batch rows each:
//                  cb[b][j] = ab0[j] + sum_k iemb_b[k]*(aW0[64+k][j]-aW0[192+k][j])
// ---------------------------------------------------------------------------
__global__ __launch_bounds__(256) void prep_kernel(
    const int* __restrict__ item_id, const float* __restrict__ item_W,
    const float* __restrict__ aW0, const float* __restrict__ ab0,
    const float* __restrict__ aW1,
    float* __restrict__ T1t, float* __restrict__ T2t,
    unsigned short* __restrict__ PW1, float* __restrict__ cb_ws)
{
    __shared__ float shbuf[3 * 64 * 65];   // 49,920 B
    const int tid = threadIdx.x;
    if (blockIdx.x == 0) {
        #pragma unroll
        for (int t = 0; t < 3; ++t) {
            const int r0 = (t == 0) ? 0 : (t == 1) ? 128 : 192;
            for (int u = tid; u < 1024; u += 256) {          // 64 rows x 16 float4
                int k = u >> 4, c4 = u & 15;
                float4 v = *(const float4*)(aW0 + (r0 + k) * 64 + c4 * 4);
                float* dst = shbuf + t * 4160 + k * 65 + c4 * 4;
                dst[0] = v.x; dst[1] = v.y; dst[2] = v.z; dst[3] = v.w;
            }
        }
        __syncthreads();
        for (int u = tid; u < 4096; u += 256) {
            int j = u >> 6, k = u & 63;
            T1t[u] = shbuf[k * 65 + j] + shbuf[2 * 4160 + k * 65 + j];
            T2t[u] = shbuf[4160 + k * 65 + j];
        }
        for (int u = tid; u < 2048; u += 256) {
            int i = u & 7, lane = (u >> 3) & 63, f = u >> 9;
            int nt = f >> 1, ks = f & 1;
            int k = ks * 32 + (lane >> 4) * 8 + i;
            int n = nt * 16 + (lane & 15);
            PW1[u] = f2bf(aW1[k * 32 + n]);
        }
    } else {
        float* T3 = shbuf;                 // [64][65]
        float* IE = shbuf + 64 * 65;       // [64][64]
        const int B0 = (blockIdx.x - 1) * 64;
        for (int u = tid; u < 4096; u += 256) {
            int k = u >> 6, j = u & 63;
            T3[k * 65 + j] = aW0[(64 + k) * 64 + j] - aW0[(192 + k) * 64 + j];
        }
        for (int u = tid; u < 4096; u += 256) {
            int r = u >> 6, j = u & 63;
            IE[r * 64 + j] = item_W[(size_t)item_id[B0 + r] * 64 + j];
        }
        __syncthreads();
        const int j = tid & 63, rg = tid >> 6;
        for (int pass = 0; pass < 16; ++pass) {
            int bl = rg * 16 + pass;
            float acc = ab0[j];
            #pragma unroll 8
            for (int k = 0; k < 64; ++k)
                acc = fmaf(IE[bl * 64 + k], T3[k * 65 + j], acc);
            cb_ws[(size_t)(B0 + bl) * 64 + j] = acc;
        }
    }
}

// ---------------------------------------------------------------------------
// attn_kernel: one block per batch element. 256 thr = 4 waves. (round-2
// structure: best measured 74.0 us, VGPR 60, no spills.)
// Deep-issued gather (14x16B loads in flight/thread before any pack).
// Changes this round: v_cvt_pk_bf16_f32 for all packing (~550 VALU ops/thread
// removed) + LDS-only barriers (no vmcnt drain). LDS 38,624 B -> 4 blocks/CU.
// ---------------------------------------------------------------------------
__global__ __launch_bounds__(256, 4) void attn_kernel(
    const int* __restrict__ item_id, const int* __restrict__ hist_seq,
    const float* __restrict__ item_W, const float* __restrict__ hist_W,
    const float* __restrict__ T1t, const float* __restrict__ T2t,
    const unsigned short* __restrict__ PW1, const float* __restrict__ cb_ws,
    const float* __restrict__ ab1, const float* __restrict__ aW2,
    const float* __restrict__ ab2, float* __restrict__ pooled_ws)
{
    __shared__ __align__(16) unsigned char smem[38624];
    unsigned short* Hs  = (unsigned short*)(smem);           // 200 x 72 bf16 = 28800 B
    unsigned short* BB  = (unsigned short*)(smem + 28800);   // 8192 B: WeT -> scr -> pools
    int*   seq_sh = (int*)(smem + 36992);                    // 200 i32
    float* scores = (float*)(smem + 37792);                  // 200 f32
    float* red    = (float*)(smem + 38592);                  // 8 f32

    const int tid  = threadIdx.x;
    const int w    = tid >> 6;
    const int lane = tid & 63;
    const int b    = blockIdx.x;
    const int* hseq = hist_seq + b * L_SZ;

    // stage seq for mask use later (independent of gather addressing below)
    if (tid < L_SZ) seq_sh[tid] = hseq[tid];

    // ---- deep gather: rows rbase+32t (t<6), plus rows 192..199 for tid<64 ----
    const int rbase = tid >> 3, c8 = tid & 7;
    const bool extra = tid < 64;
    const int r6 = extra ? 192 + rbase : 0;
    const float* sp[7];
    #pragma unroll
    for (int t = 0; t < 6; ++t)
        sp[t] = hist_W + (size_t)hseq[rbase + t * 32] * 64 + c8 * 8;
    sp[6] = hist_W + (size_t)hseq[r6] * 64 + c8 * 8;
    float4 f0[7], f1[7];
    #pragma unroll
    for (int t = 0; t < 7; ++t) {
        f0[t] = *(const float4*)sp[t];
        f1[t] = *(const float4*)(sp[t] + 4);
    }

    // ---- issue batch-invariant loads while the gather is in flight ----
    const int c = lane & 15, q = lane >> 4;
    short8 bW1[2][2];
    #pragma unroll
    for (int nt = 0; nt < 2; ++nt)
        #pragma unroll
        for (int ks = 0; ks < 2; ++ks)
            bW1[nt][ks] = *(const short8*)(PW1 + ((nt * 2 + ks) * 64 + lane) * 8);
    float cbr[4];
    #pragma unroll
    for (int nt = 0; nt < 4; ++nt) cbr[nt] = cb_ws[(size_t)b * 64 + nt * 16 + c];
    float ab1r[2], aw2r[2];
    #pragma unroll
    for (int nt = 0; nt < 2; ++nt) {
        ab1r[nt] = ab1[nt * 16 + c];
        aw2r[nt] = aW2[nt * 16 + c];
    }
    const float ab2s = ab2[0];

    // ---- pack gather -> Hs (per-use vmcnt keeps later loads outstanding) ----
    #pragma unroll
    for (int t = 0; t < 6; ++t) {
        uint4 pk;
        pk.x = pk2(f0[t].x, f0[t].y); pk.y = pk2(f0[t].z, f0[t].w);
        pk.z = pk2(f1[t].x, f1[t].y); pk.w = pk2(f1[t].z, f1[t].w);
        *(uint4*)(Hs + (rbase + t * 32) * HS_STRIDE + c8 * 8) = pk;
    }
    if (extra) {
        uint4 pk;
        pk.x = pk2(f0[6].x, f0[6].y); pk.y = pk2(f0[6].z, f0[6].w);
        pk.z = pk2(f1[6].x, f1[6].y); pk.w = pk2(f1[6].z, f1[6].w);
        *(uint4*)(Hs + r6 * HS_STRIDE + c8 * 8) = pk;
    }

    // ---- WeT build from prepacked tables: bf16(T1 + iemb*T2), swizzled ----
    {
        const float* irow = item_W + (size_t)item_id[b] * 64;
        const int j0 = tid >> 3;   // 0..31
        float4 em0 = *(const float4*)(irow + c8 * 8);
        float4 em1 = *(const float4*)(irow + c8 * 8 + 4);
        #pragma unroll
        for (int t = 0; t < 2; ++t) {
            int j = j0 + t * 32;
            const float* p1 = T1t + j * 64 + c8 * 8;
            const float* p2 = T2t + j * 64 + c8 * 8;
            float4 a0 = *(const float4*)p1, a1 = *(const float4*)(p1 + 4);
            float4 b0 = *(const float4*)p2, b1 = *(const float4*)(p2 + 4);
            float v[8];
            v[0] = a0.x + em0.x * b0.x; v[1] = a0.y + em0.y * b0.y;
            v[2] = a0.z + em0.z * b0.z; v[3] = a0.w + em0.w * b0.w;
            v[4] = a1.x + em1.x * b1.x; v[5] = a1.y + em1.y * b1.y;
            v[6] = a1.z + em1.z * b1.z; v[7] = a1.w + em1.w * b1.w;
            uint4 pk;
            pk.x = pk2(v[0], v[1]); pk.y = pk2(v[2], v[3]);
            pk.z = pk2(v[4], v[5]); pk.w = pk2(v[6], v[7]);
            *(uint4*)(BB + j * 64 + (c8 ^ (j & 7)) * 8) = pk;
        }
    }
    bar_lds();   // #1: Hs + WeT visible

    // ---- hoist bW frags from swizzled WeT ----
    short8 bW[4][2];
    #pragma unroll
    for (int nt = 0; nt < 4; ++nt)
        #pragma unroll
        for (int ks = 0; ks < 2; ++ks)
            bW[nt][ks] = *(const short8*)(BB + (nt * 16 + c) * 64
                                             + ((4 * ks + q) ^ (c & 7)) * 8);
    bar_lds();   // #2: BB free for scr

    unsigned short* scrw = BB + w * (16 * 64);
    const floatx4 zf = {0.f, 0.f, 0.f, 0.f};

    // ---- main: per M-tile  layer0 MFMA -> relu -> scr -> layer1 MFMA -> score ----
    // (tile 12 rows 200..207 read garbage beyond Hs -> rows are independent, masked)
    for (int mt = w; mt < 13; mt += 4) {
        const int rowbase = mt * 16;
        floatx4 acc0[4] = {zf, zf, zf, zf};
        #pragma unroll
        for (int ks = 0; ks < 2; ++ks) {
            short8 a = *(const short8*)(Hs + (rowbase + c) * HS_STRIDE + ks * 32 + q * 8);
            acc0[0] = __builtin_amdgcn_mfma_f32_16x16x32_bf16(a, bW[0][ks], acc0[0], 0, 0, 0);
            acc0[1] = __builtin_amdgcn_mfma_f32_16x16x32_bf16(a, bW[1][ks], acc0[1], 0, 0, 0);
            acc0[2] = __builtin_amdgcn_mfma_f32_16x16x32_bf16(a, bW[2][ks], acc0[2], 0, 0, 0);
            acc0[3] = __builtin_amdgcn_mfma_f32_16x16x32_bf16(a, bW[3][ks], acc0[3], 0, 0, 0);
        }
        // epilogue: +cb, relu, bf16 via cvt_pk pairs (rows r,r+1 share a cvt)
        #pragma unroll
        for (int nt = 0; nt < 4; ++nt)
            #pragma unroll
            for (int r = 0; r < 4; r += 2) {
                float h0 = fmaxf(acc0[nt][r]     + cbr[nt], 0.f);
                float h1 = fmaxf(acc0[nt][r + 1] + cbr[nt], 0.f);
                unsigned int u = pk2(h0, h1);
                int row0 = q * 4 + r;
                int row1 = row0 + 1;
                int gp0 = (2 * nt + (c >> 3)) ^ (row0 & 7);
                int gp1 = (2 * nt + (c >> 3)) ^ (row1 & 7);
                scrw[row0 * 64 + gp0 * 8 + (c & 7)] = (unsigned short)u;
                scrw[row1 * 64 + gp1 * 8 + (c & 7)] = (unsigned short)(u >> 16);
            }
        floatx4 acc1[2] = {zf, zf};
        #pragma unroll
        for (int ks = 0; ks < 2; ++ks) {
            short8 a1 = *(const short8*)(scrw + c * 64 + ((4 * ks + q) ^ (c & 7)) * 8);
            acc1[0] = __builtin_amdgcn_mfma_f32_16x16x32_bf16(a1, bW1[0][ks], acc1[0], 0, 0, 0);
            acc1[1] = __builtin_amdgcn_mfma_f32_16x16x32_bf16(a1, bW1[1][ks], acc1[1], 0, 0, 0);
        }
        // layer2: relu -> *aW2 -> reduce over the 16 col-lanes
        float s[4];
        #pragma unroll
        for (int r = 0; r < 4; ++r)
            s[r] = fmaxf(acc1[0][r] + ab1r[0], 0.f) * aw2r[0]
                 + fmaxf(acc1[1][r] + ab1r[1], 0.f) * aw2r[1];
        #pragma unroll
        for (int m = 1; m <= 8; m <<= 1)
            #pragma unroll
            for (int r = 0; r < 4; ++r) s[r] += __shfl_xor(s[r], m, 64);
        if (c == 0) {
            #pragma unroll
            for (int r = 0; r < 4; ++r) {
                int l = rowbase + q * 4 + r;
                if (l < L_SZ)
                    scores[l] = (seq_sh[l] == 0) ? -1.0e9f : (s[r] + ab2s);
            }
        }
    }
    bar_lds();

    // ---- masked softmax over 200 scores ----
    float s0 = (tid < L_SZ) ? scores[tid] : -3.0e38f;
    float mx = wave_max64(s0);
    if (lane == 0) red[w] = mx;
    bar_lds();
    mx = fmaxf(fmaxf(red[0], red[1]), fmaxf(red[2], red[3]));
    float e = (tid < L_SZ) ? __expf(s0 - mx) : 0.f;
    float sm = wave_sum64(e);
    if (lane == 0) red[4 + w] = sm;
    bar_lds();
    const float winv = 1.f / ((red[4] + red[5]) + (red[6] + red[7]));
    if (tid < L_SZ) scores[tid] = e * winv;
    bar_lds();

    // ---- pooled[j] = sum_l w_l * H[l][j]; 8 row-groups x (2 cols / lane) ----
    float* pools = (float*)BB;   // scr dead now
    {
        int g  = (w << 1) | (lane >> 5);
        int jj = lane & 31;
        int l0 = g * 26, l1 = (l0 + 26 < L_SZ) ? l0 + 26 : L_SZ;
        float p0 = 0.f, p1 = 0.f;
        for (int l = l0; l < l1; ++l) {
            float wt = scores[l];
            unsigned int pv = *(const unsigned int*)(Hs + l * HS_STRIDE + jj * 2);
            p0 = fmaf(wt, bf2f((unsigned short)(pv & 0xffffu)), p0);
            p1 = fmaf(wt, bf2f((unsigned short)(pv >> 16)), p1);
        }
        float2 pp = {p0, p1};
        *(float2*)&pools[g * 64 + jj * 2] = pp;
    }
    bar_lds();
    if (tid < 64) {
        float sum = 0.f;
        #pragma unroll
        for (int g = 0; g < 8; ++g) sum += pools[g * 64 + tid];
        pooled_ws[(size_t)b * 64 + tid] = sum;
    }
}

// Main MLP: 244 -> 256 -> 128 -> 1 -> sigmoid. One block per RB=8 rows.
__global__ __launch_bounds__(256) void mlp_kernel(
    const int* __restrict__ user_id, const int* __restrict__ item_id,
    const int* __restrict__ item_cat, const int* __restrict__ item_dur,
    const float* __restrict__ user_dense, const float* __restrict__ item_dense,
    const float* __restrict__ user_W, const float* __restrict__ item_W,
    const float* __restrict__ cat_W, const float* __restrict__ dur_W,
    const float* __restrict__ mW0, const float* __restrict__ mb0,
    const float* __restrict__ mW1, const float* __restrict__ mb1,
    const float* __restrict__ mW2, const float* __restrict__ mb2,
    const float* __restrict__ pooled_ws, float* __restrict__ out)
{
    __shared__ __align__(16) float xT[244][RB];
    __shared__ __align__(16) float h0T[256][RB];
    __shared__ __align__(16) float h1T[128][RB];
    __shared__ __align__(16) float part[128][RB];

    const int tid = threadIdx.x;
    const int b0 = blockIdx.x * RB;

    for (int idx = tid; idx < 244 * RB; idx += 256) {
        int r = idx / 244;
        int c = idx - r * 244;
        int b = b0 + r;
        float v;
        if (c < 64)       v = user_W[(size_t)user_id[b] * 64 + c];
        else if (c < 128) v = item_W[(size_t)item_id[b] * 64 + (c - 64)];
        else if (c < 144) v = cat_W[item_cat[b] * 16 + (c - 128)];
        else if (c < 152) v = dur_W[item_dur[b] * 8 + (c - 144)];
        else if (c < 177) v = user_dense[b * 25 + (c - 152)];
        else if (c < 180) v = item_dense[b * 3 + (c - 177)];
        else              v = pooled_ws[(size_t)b * 64 + (c - 180)];
        xT[c][r] = v;
    }
    __syncthreads();

    {
        float acc[RB];
        const float bias = mb0[tid];
        #pragma unroll
        for (int r = 0; r < RB; ++r) acc[r] = bias;
        #pragma unroll 4
        for (int k = 0; k < 244; ++k) {
            float wk = mW0[k * 256 + tid];
            float4 xa = *(const float4*)&xT[k][0];
            float4 xb = *(const float4*)&xT[k][4];
            acc[0] = fmaf(wk, xa.x, acc[0]);
            acc[1] = fmaf(wk, xa.y, acc[1]);
            acc[2] = fmaf(wk, xa.z, acc[2]);
            acc[3] = fmaf(wk, xa.w, acc[3]);
            acc[4] = fmaf(wk, xb.x, acc[4]);
            acc[5] = fmaf(wk, xb.y, acc[5]);
            acc[6] = fmaf(wk, xb.z, acc[6]);
            acc[7] = fmaf(wk, xb.w, acc[7]);
        }
        #pragma unroll
        for (int r = 0; r < RB; ++r) h0T[tid][r] = fmaxf(acc[r], 0.f);
    }
    __syncthreads();

    const int jj = tid & 127;
    const int half = tid >> 7;
    {
        float acc[RB];
        #pragma unroll
        for (int r = 0; r < RB; ++r) acc[r] = 0.f;
        #pragma unroll 4
        for (int t = 0; t < 128; ++t) {
            int k = half * 128 + t;
            float wk = mW1[k * 128 + jj];
            float4 ha = *(const float4*)&h0T[k][0];
            float4 hb = *(const float4*)&h0T[k][4];
            acc[0] = fmaf(wk, ha.x, acc[0]);
            acc[1] = fmaf(wk, ha.y, acc[1]);
            acc[2] = fmaf(wk, ha.z, acc[2]);
            acc[3] = fmaf(wk, ha.w, acc[3]);
            acc[4] = fmaf(wk, hb.x, acc[4]);
            acc[5] = fmaf(wk, hb.y, acc[5]);
            acc[6] = fmaf(wk, hb.z, acc[6]);
            acc[7] = fmaf(wk, hb.w, acc[7]);
        }
        if (half == 1) {
            #pragma unroll
            for (int r = 0; r < RB; ++r) part[jj][r] = acc[r];
        }
        __syncthreads();
        if (half == 0) {
            const float bias = mb1[jj];
            #pragma unroll
            for (int r = 0; r < RB; ++r)
                h1T[jj][r] = fmaxf(acc[r] + part[jj][r] + bias, 0.f);
        }
    }
    __syncthreads();

    if (tid < RB) {
        const int r = tid;
        float a0 = mb2[0], a1 = 0.f;
        #pragma unroll 8
        for (int k = 0; k < 128; k += 2) {
            a0 = fmaf(h1T[k][r],     mW2[k],     a0);
            a1 = fmaf(h1T[k + 1][r], mW2[k + 1], a1);
        }
        float a = a0 + a1;
        out[b0 + r] = 1.f / (1.f + __expf(-a));
    }
}

extern "C" void kernel_launch(void* const* d_in, const int* in_sizes, int n_in,
                              void* d_out, int out_size, void* d_ws, size_t ws_size,
                              hipStream_t stream) {
    (void)in_sizes; (void)n_in; (void)out_size; (void)ws_size;
    const int*   user_id    = (const int*)d_in[0];
    const int*   item_id    = (const int*)d_in[1];
    const int*   item_cat   = (const int*)d_in[2];
    const int*   item_dur   = (const int*)d_in[3];
    const float* user_dense = (const float*)d_in[4];
    const float* item_dense = (const float*)d_in[5];
    const int*   hist_seq   = (const int*)d_in[6];
    const float* user_W     = (const float*)d_in[7];
    const float* item_W     = (const float*)d_in[8];
    const float* cat_W      = (const float*)d_in[9];
    const float* dur_W      = (const float*)d_in[10];
    const float* hist_W     = (const float*)d_in[11];
    const float* aW0 = (const float*)d_in[12];
    const float* ab0 = (const float*)d_in[13];
    const float* aW1 = (const float*)d_in[14];
    const float* ab1 = (const float*)d_in[15];
    const float* aW2 = (const float*)d_in[16];
    const float* ab2 = (const float*)d_in[17];
    const float* mW0 = (const float*)d_in[18];
    const float* mb0 = (const float*)d_in[19];
    const float* mW1 = (const float*)d_in[20];
    const float* mb1 = (const float*)d_in[21];
    const float* mW2 = (const float*)d_in[22];
    const float* mb2 = (const float*)d_in[23];
    float* out = (float*)d_out;

    // workspace: pooled 1MB | cb 1MB | T1t 16KB | T2t 16KB | PW1 4KB
    char* ws = (char*)d_ws;
    float* pooled_ws = (float*)ws;                               // 4096*64 f32
    float* cb_ws     = (float*)(ws + (1u << 20));                // 4096*64 f32
    float* T1t       = (float*)(ws + (2u << 20));                // 64*64 f32
    float* T2t       = (float*)(ws + (2u << 20) + 16384);        // 64*64 f32
    unsigned short* PW1 = (unsigned short*)(ws + (2u << 20) + 32768); // 2048 bf16

    prep_kernel<<<65, 256, 0, stream>>>(item_id, item_W, aW0, ab0, aW1,
                                        T1t, T2t, PW1, cb_ws);
    attn_kernel<<<4096, 256, 0, stream>>>(item_id, hist_seq, item_W, hist_W,
                                          T1t, T2t, PW1, cb_ws,
                                          ab1, aW2, ab2, pooled_ws);
    mlp_kernel<<<4096 / RB, 256, 0, stream>>>(user_id, item_id, item_cat, item_dur,
                                              user_dense, item_dense,
                                              user_W, item_W, cat_W, dur_W,
                                              mW0, mb0, mW1, mb1, mW2, mb2,
                                              pooled_ws, out);
}

// Round 6
// 393.875 us; speedup vs baseline: 1.3510x; 1.0124x over previous
//
#include <hip/hip_runtime.h>

#define L_SZ 200
#define RB 8
#define HS_STRIDE 72   // bf16 elems per H row: 64 + 8 pad (144 B, 16B-aligned)

typedef __attribute__((ext_vector_type(8))) short short8;   // 8 bf16 = 4 VGPRs (MFMA A/B frag)
typedef __attribute__((ext_vector_type(4))) float floatx4;  // MFMA C/D frag

__device__ __forceinline__ float bf2f(unsigned short h) {
    return __uint_as_float(((unsigned int)h) << 16);
}
// HW packed convert: 1 instruction, RNE. low16 = bf16(a), high16 = bf16(b).
__device__ __forceinline__ unsigned int pk2(float a, float b) {
    unsigned int r;
    asm("v_cvt_pk_bf16_f32 %0, %1, %2" : "=v"(r) : "v"(a), "v"(b));
    return r;
}
__device__ __forceinline__ unsigned short bf1(float a) {
    return (unsigned short)(pk2(a, a) & 0xffffu);
}
__device__ __forceinline__ float wave_sum64(float v) {
    #pragma unroll
    for (int m = 1; m <= 32; m <<= 1) v += __shfl_xor(v, m, 64);
    return v;
}
__device__ __forceinline__ float wave_max64(float v) {
    #pragma unroll
    for (int m = 1; m <= 32; m <<= 1) v = fmaxf(v, __shfl_xor(v, m, 64));
    return v;
}
// LDS-only barrier: waits LDS ops but does NOT drain vmcnt -> early-issued
// global loads stay in flight across it. All intra-block comms are via LDS.
__device__ __forceinline__ void bar_lds() {
    asm volatile("s_waitcnt lgkmcnt(0)" ::: "memory");
    __builtin_amdgcn_s_barrier();
    asm volatile("" ::: "memory");
}

// ---------------------------------------------------------------------------
// attn_kernel: one block per batch element, 256 thr = 4 waves. SELF-CONTAINED
// (no prep kernel): session ledger shows the only zero-overhead timed window
// was the 2-kernel layout (R0 gap ~0 vs ~100-145 us for every 3-kernel round).
// In-block per-element work, all burst-issued / L2-hot:
//   - deep gather: 14x16B hist_W loads in flight before any pack (R1)
//   - bW1 direct from aW1 (32 L2-hot scalars, issued under the gather)
//   - WeT build WITHOUT transposed tables: thread (kk=tid>>2, jq=tid&3) reads
//     aW0 rows {kk,64+kk,128+kk,192+kk} x 16-col j-slice (row-major coalesced),
//     writes 16 swizzled b16 LDS vals matching the b128 hoist layout
//   - cb = ab0 + iemb.(A1-A3): same loads, 4-step shfl_xor k-reduce (lanes
//     stride-4 share j), wave partials in 1KB LDS, finalized after barrier #1
//     (R3's failure was scattered serial loads between barriers; these arrive
//     in the same coalesced burst)
// cvt_pk packing + LDS-only barriers kept from R5.
// LDS 39,648 B -> 4 blocks/CU. Reg sequencing: gather (56) retires before the
// 16-float4 aW0 burst (64) -> peak ~115 < 128 cap (R4 spill lesson).
// ---------------------------------------------------------------------------
__global__ __launch_bounds__(256, 4) void attn_kernel(
    const int* __restrict__ item_id, const int* __restrict__ hist_seq,
    const float* __restrict__ item_W, const float* __restrict__ hist_W,
    const float* __restrict__ aW0, const float* __restrict__ ab0,
    const float* __restrict__ aW1, const float* __restrict__ ab1,
    const float* __restrict__ aW2, const float* __restrict__ ab2,
    float* __restrict__ pooled_ws)
{
    __shared__ __align__(16) unsigned char smem[39648];
    unsigned short* Hs  = (unsigned short*)(smem);           // 200 x 72 bf16 = 28800 B
    unsigned short* BB  = (unsigned short*)(smem + 28800);   // 8192 B: WeT -> scr -> pools
    int*   seq_sh = (int*)(smem + 36992);                    // 200 i32
    float* scores = (float*)(smem + 37792);                  // 200 f32
    float* red    = (float*)(smem + 38592);                  // 8 f32
    float* cbp    = (float*)(smem + 38624);                  // 4 x 64 f32 wave partials

    const int tid  = threadIdx.x;
    const int w    = tid >> 6;
    const int lane = tid & 63;
    const int b    = blockIdx.x;
    const int* hseq = hist_seq + b * L_SZ;

    // stage seq for mask use later
    if (tid < L_SZ) seq_sh[tid] = hseq[tid];

    // ---- deep gather: rows rbase+32t (t<6), plus rows 192..199 for tid<64 ----
    const int rbase = tid >> 3, c8 = tid & 7;
    const bool extra = tid < 64;
    const int r6 = extra ? 192 + rbase : 0;
    const float* sp[7];
    #pragma unroll
    for (int t = 0; t < 6; ++t)
        sp[t] = hist_W + (size_t)hseq[rbase + t * 32] * 64 + c8 * 8;
    sp[6] = hist_W + (size_t)hseq[r6] * 64 + c8 * 8;
    float4 f0[7], f1[7];
    #pragma unroll
    for (int t = 0; t < 7; ++t) {
        f0[t] = *(const float4*)sp[t];
        f1[t] = *(const float4*)(sp[t] + 4);
    }

    // ---- batch-invariant loads issued while the gather is in flight ----
    const int c = lane & 15, q = lane >> 4;
    short8 bW1[2][2];
    #pragma unroll
    for (int nt = 0; nt < 2; ++nt)
        #pragma unroll
        for (int ks = 0; ks < 2; ++ks) {
            float v[8];
            #pragma unroll
            for (int i = 0; i < 8; ++i)
                v[i] = aW1[(ks * 32 + q * 8 + i) * 32 + nt * 16 + c];
            uint4 uu;
            uu.x = pk2(v[0], v[1]); uu.y = pk2(v[2], v[3]);
            uu.z = pk2(v[4], v[5]); uu.w = pk2(v[6], v[7]);
            short8 r; *(uint4*)&r = uu;
            bW1[nt][ks] = r;
        }
    float ab0r[4];
    #pragma unroll
    for (int nt = 0; nt < 4; ++nt) ab0r[nt] = ab0[nt * 16 + c];
    float ab1r[2], aw2r[2];
    #pragma unroll
    for (int nt = 0; nt < 2; ++nt) {
        ab1r[nt] = ab1[nt * 16 + c];
        aw2r[nt] = aW2[nt * 16 + c];
    }
    const float ab2s = ab2[0];

    // ---- pack gather -> Hs (frees the 56 gather VGPRs) ----
    #pragma unroll
    for (int t = 0; t < 6; ++t) {
        uint4 pk;
        pk.x = pk2(f0[t].x, f0[t].y); pk.y = pk2(f0[t].z, f0[t].w);
        pk.z = pk2(f1[t].x, f1[t].y); pk.w = pk2(f1[t].z, f1[t].w);
        *(uint4*)(Hs + (rbase + t * 32) * HS_STRIDE + c8 * 8) = pk;
    }
    if (extra) {
        uint4 pk;
        pk.x = pk2(f0[6].x, f0[6].y); pk.y = pk2(f0[6].z, f0[6].w);
        pk.z = pk2(f1[6].x, f1[6].y); pk.w = pk2(f1[6].z, f1[6].w);
        *(uint4*)(Hs + r6 * HS_STRIDE + c8 * 8) = pk;
    }

    // ---- WeT + cb build: thread (kk, jq) owns k=kk, j in [jq*16, jq*16+16) ----
    // WeT[j][k] = aW0[k][j] + aW0[192+k][j] + ie[k]*aW0[128+k][j]  (bf16, swizzled)
    // cb[j]     = ab0[j] + sum_k ie[k]*(aW0[64+k][j] - aW0[192+k][j])
    {
        const int kk = tid >> 2;     // 0..63
        const int jq = tid & 3;      // j-quarter
        const float ie_k = item_W[(size_t)item_id[b] * 64 + kk];
        const float4* a0p = (const float4*)(aW0 + kk * 64 + jq * 16);
        const float4* a1p = (const float4*)(aW0 + (64 + kk) * 64 + jq * 16);
        const float4* a2p = (const float4*)(aW0 + (128 + kk) * 64 + jq * 16);
        const float4* a3p = (const float4*)(aW0 + (192 + kk) * 64 + jq * 16);
        float4 A0[4], A1[4], A2[4], A3[4];
        #pragma unroll
        for (int t = 0; t < 4; ++t) {
            A0[t] = a0p[t]; A1[t] = a1p[t]; A2[t] = a2p[t]; A3[t] = a3p[t];
        }
        const int k8g = kk >> 3, k7 = kk & 7;
        float cbv[16];
        #pragma unroll
        for (int t = 0; t < 4; ++t) {
            const float* p0 = (const float*)&A0[t];
            const float* p1 = (const float*)&A1[t];
            const float* p2 = (const float*)&A2[t];
            const float* p3 = (const float*)&A3[t];
            #pragma unroll
            for (int u = 0; u < 4; ++u) {
                int j = jq * 16 + t * 4 + u;
                float we = p0[u] + p3[u] + ie_k * p2[u];
                BB[j * 64 + ((k8g ^ (j & 7)) << 3) + k7] = bf1(we);
                cbv[t * 4 + u] = ie_k * (p1[u] - p3[u]);
            }
        }
        // k-reduce within wave: lanes stride-4 share (jq, j); kk spans w*16..+16
        #pragma unroll
        for (int t = 0; t < 16; ++t) {
            float p = cbv[t];
            p += __shfl_xor(p, 4, 64);
            p += __shfl_xor(p, 8, 64);
            p += __shfl_xor(p, 16, 64);
            p += __shfl_xor(p, 32, 64);
            cbv[t] = p;
        }
        if ((lane >> 2) == 0) {
            #pragma unroll
            for (int t = 0; t < 16; ++t)
                cbp[w * 64 + jq * 16 + t] = cbv[t];
        }
    }
    bar_lds();   // #1: Hs + WeT + cbp visible

    // ---- hoist bW frags from swizzled WeT; finalize cb ----
    short8 bW[4][2];
    #pragma unroll
    for (int nt = 0; nt < 4; ++nt)
        #pragma unroll
        for (int ks = 0; ks < 2; ++ks)
            bW[nt][ks] = *(const short8*)(BB + (nt * 16 + c) * 64
                                             + ((4 * ks + q) ^ (c & 7)) * 8);
    float cbr[4];
    #pragma unroll
    for (int nt = 0; nt < 4; ++nt) {
        int j = nt * 16 + c;
        cbr[nt] = ab0r[nt] + ((cbp[j] + cbp[64 + j]) + (cbp[128 + j] + cbp[192 + j]));
    }
    bar_lds();   // #2: BB free for scr

    unsigned short* scrw = BB + w * (16 * 64);
    const floatx4 zf = {0.f, 0.f, 0.f, 0.f};

    // ---- main: per M-tile  layer0 MFMA -> relu -> scr -> layer1 MFMA -> score ----
    // (tile 12 rows 200..207 read garbage beyond Hs -> rows are independent, masked)
    for (int mt = w; mt < 13; mt += 4) {
        const int rowbase = mt * 16;
        floatx4 acc0[4] = {zf, zf, zf, zf};
        #pragma unroll
        for (int ks = 0; ks < 2; ++ks) {
            short8 a = *(const short8*)(Hs + (rowbase + c) * HS_STRIDE + ks * 32 + q * 8);
            acc0[0] = __builtin_amdgcn_mfma_f32_16x16x32_bf16(a, bW[0][ks], acc0[0], 0, 0, 0);
            acc0[1] = __builtin_amdgcn_mfma_f32_16x16x32_bf16(a, bW[1][ks], acc0[1], 0, 0, 0);
            acc0[2] = __builtin_amdgcn_mfma_f32_16x16x32_bf16(a, bW[2][ks], acc0[2], 0, 0, 0);
            acc0[3] = __builtin_amdgcn_mfma_f32_16x16x32_bf16(a, bW[3][ks], acc0[3], 0, 0, 0);
        }
        // epilogue: +cb, relu, bf16 via cvt_pk pairs (rows r,r+1 share a cvt)
        #pragma unroll
        for (int nt = 0; nt < 4; ++nt)
            #pragma unroll
            for (int r = 0; r < 4; r += 2) {
                float h0 = fmaxf(acc0[nt][r]     + cbr[nt], 0.f);
                float h1 = fmaxf(acc0[nt][r + 1] + cbr[nt], 0.f);
                unsigned int u = pk2(h0, h1);
                int row0 = q * 4 + r;
                int row1 = row0 + 1;
                int gp0 = (2 * nt + (c >> 3)) ^ (row0 & 7);
                int gp1 = (2 * nt + (c >> 3)) ^ (row1 & 7);
                scrw[row0 * 64 + gp0 * 8 + (c & 7)] = (unsigned short)u;
                scrw[row1 * 64 + gp1 * 8 + (c & 7)] = (unsigned short)(u >> 16);
            }
        floatx4 acc1[2] = {zf, zf};
        #pragma unroll
        for (int ks = 0; ks < 2; ++ks) {
            short8 a1 = *(const short8*)(scrw + c * 64 + ((4 * ks + q) ^ (c & 7)) * 8);
            acc1[0] = __builtin_amdgcn_mfma_f32_16x16x32_bf16(a1, bW1[0][ks], acc1[0], 0, 0, 0);
            acc1[1] = __builtin_amdgcn_mfma_f32_16x16x32_bf16(a1, bW1[1][ks], acc1[1], 0, 0, 0);
        }
        // layer2: relu -> *aW2 -> reduce over the 16 col-lanes
        float s[4];
        #pragma unroll
        for (int r = 0; r < 4; ++r)
            s[r] = fmaxf(acc1[0][r] + ab1r[0], 0.f) * aw2r[0]
                 + fmaxf(acc1[1][r] + ab1r[1], 0.f) * aw2r[1];
        #pragma unroll
        for (int m = 1; m <= 8; m <<= 1)
            #pragma unroll
            for (int r = 0; r < 4; ++r) s[r] += __shfl_xor(s[r], m, 64);
        if (c == 0) {
            #pragma unroll
            for (int r = 0; r < 4; ++r) {
                int l = rowbase + q * 4 + r;
                if (l < L_SZ)
                    scores[l] = (seq_sh[l] == 0) ? -1.0e9f : (s[r] + ab2s);
            }
        }
    }
    bar_lds();

    // ---- masked softmax over 200 scores ----
    float s0 = (tid < L_SZ) ? scores[tid] : -3.0e38f;
    float mx = wave_max64(s0);
    if (lane == 0) red[w] = mx;
    bar_lds();
    mx = fmaxf(fmaxf(red[0], red[1]), fmaxf(red[2], red[3]));
    float e = (tid < L_SZ) ? __expf(s0 - mx) : 0.f;
    float sm = wave_sum64(e);
    if (lane == 0) red[4 + w] = sm;
    bar_lds();
    const float winv = 1.f / ((red[4] + red[5]) + (red[6] + red[7]));
    if (tid < L_SZ) scores[tid] = e * winv;
    bar_lds();

    // ---- pooled[j] = sum_l w_l * H[l][j]; 8 row-groups x (2 cols / lane) ----
    float* pools = (float*)BB;   // scr dead now
    {
        int g  = (w << 1) | (lane >> 5);
        int jj = lane & 31;
        int l0 = g * 26, l1 = (l0 + 26 < L_SZ) ? l0 + 26 : L_SZ;
        float p0 = 0.f, p1 = 0.f;
        for (int l = l0; l < l1; ++l) {
            float wt = scores[l];
            unsigned int pv = *(const unsigned int*)(Hs + l * HS_STRIDE + jj * 2);
            p0 = fmaf(wt, bf2f((unsigned short)(pv & 0xffffu)), p0);
            p1 = fmaf(wt, bf2f((unsigned short)(pv >> 16)), p1);
        }
        float2 pp = {p0, p1};
        *(float2*)&pools[g * 64 + jj * 2] = pp;
    }
    bar_lds();
    if (tid < 64) {
        float sum = 0.f;
        #pragma unroll
        for (int g = 0; g < 8; ++g) sum += pools[g * 64 + tid];
        pooled_ws[(size_t)b * 64 + tid] = sum;
    }
}

// Main MLP: 244 -> 256 -> 128 -> 1 -> sigmoid. One block per RB=8 rows.
__global__ __launch_bounds__(256) void mlp_kernel(
    const int* __restrict__ user_id, const int* __restrict__ item_id,
    const int* __restrict__ item_cat, const int* __restrict__ item_dur,
    const float* __restrict__ user_dense, const float* __restrict__ item_dense,
    const float* __restrict__ user_W, const float* __restrict__ item_W,
    const float* __restrict__ cat_W, const float* __restrict__ dur_W,
    const float* __restrict__ mW0, const float* __restrict__ mb0,
    const float* __restrict__ mW1, const float* __restrict__ mb1,
    const float* __restrict__ mW2, const float* __restrict__ mb2,
    const float* __restrict__ pooled_ws, float* __restrict__ out)
{
    __shared__ __align__(16) float xT[244][RB];
    __shared__ __align__(16) float h0T[256][RB];
    __shared__ __align__(16) float h1T[128][RB];
    __shared__ __align__(16) float part[128][RB];

    const int tid = threadIdx.x;
    const int b0 = blockIdx.x * RB;

    for (int idx = tid; idx < 244 * RB; idx += 256) {
        int r = idx / 244;
        int c = idx - r * 244;
        int b = b0 + r;
        float v;
        if (c < 64)       v = user_W[(size_t)user_id[b] * 64 + c];
        else if (c < 128) v = item_W[(size_t)item_id[b] * 64 + (c - 64)];
        else if (c < 144) v = cat_W[item_cat[b] * 16 + (c - 128)];
        else if (c < 152) v = dur_W[item_dur[b] * 8 + (c - 144)];
        else if (c < 177) v = user_dense[b * 25 + (c - 152)];
        else if (c < 180) v = item_dense[b * 3 + (c - 177)];
        else              v = pooled_ws[(size_t)b * 64 + (c - 180)];
        xT[c][r] = v;
    }
    __syncthreads();

    {
        float acc[RB];
        const float bias = mb0[tid];
        #pragma unroll
        for (int r = 0; r < RB; ++r) acc[r] = bias;
        #pragma unroll 4
        for (int k = 0; k < 244; ++k) {
            float wk = mW0[k * 256 + tid];
            float4 xa = *(const float4*)&xT[k][0];
            float4 xb = *(const float4*)&xT[k][4];
            acc[0] = fmaf(wk, xa.x, acc[0]);
            acc[1] = fmaf(wk, xa.y, acc[1]);
            acc[2] = fmaf(wk, xa.z, acc[2]);
            acc[3] = fmaf(wk, xa.w, acc[3]);
            acc[4] = fmaf(wk, xb.x, acc[4]);
            acc[5] = fmaf(wk, xb.y, acc[5]);
            acc[6] = fmaf(wk, xb.z, acc[6]);
            acc[7] = fmaf(wk, xb.w, acc[7]);
        }
        #pragma unroll
        for (int r = 0; r < RB; ++r) h0T[tid][r] = fmaxf(acc[r], 0.f);
    }
    __syncthreads();

    const int jj = tid & 127;
    const int half = tid >> 7;
    {
        float acc[RB];
        #pragma unroll
        for (int r = 0; r < RB; ++r) acc[r] = 0.f;
        #pragma unroll 4
        for (int t = 0; t < 128; ++t) {
            int k = half * 128 + t;
            float wk = mW1[k * 128 + jj];
            float4 ha = *(const float4*)&h0T[k][0];
            float4 hb = *(const float4*)&h0T[k][4];
            acc[0] = fmaf(wk, ha.x, acc[0]);
            acc[1] = fmaf(wk, ha.y, acc[1]);
            acc[2] = fmaf(wk, ha.z, acc[2]);
            acc[3] = fmaf(wk, ha.w, acc[3]);
            acc[4] = fmaf(wk, hb.x, acc[4]);
            acc[5] = fmaf(wk, hb.y, acc[5]);
            acc[6] = fmaf(wk, hb.z, acc[6]);
            acc[7] = fmaf(wk, hb.w, acc[7]);
        }
        if (half == 1) {
            #pragma unroll
            for (int r = 0; r < RB; ++r) part[jj][r] = acc[r];
        }
        __syncthreads();
        if (half == 0) {
            const float bias = mb1[jj];
            #pragma unroll
            for (int r = 0; r < RB; ++r)
                h1T[jj][r] = fmaxf(acc[r] + part[jj][r] + bias, 0.f);
        }
    }
    __syncthreads();

    if (tid < RB) {
        const int r = tid;
        float a0 = mb2[0], a1 = 0.f;
        #pragma unroll 8
        for (int k = 0; k < 128; k += 2) {
            a0 = fmaf(h1T[k][r],     mW2[k],     a0);
            a1 = fmaf(h1T[k + 1][r], mW2[k + 1], a1);
        }
        float a = a0 + a1;
        out[b0 + r] = 1.f / (1.f + __expf(-a));
    }
}

extern "C" void kernel_launch(void* const* d_in, const int* in_sizes, int n_in,
                              void* d_out, int out_size, void* d_ws, size_t ws_size,
                              hipStream_t stream) {
    (void)in_sizes; (void)n_in; (void)out_size; (void)ws_size;
    const int*   user_id    = (const int*)d_in[0];
    const int*   item_id    = (const int*)d_in[1];
    const int*   item_cat   = (const int*)d_in[2];
    const int*   item_dur   = (const int*)d_in[3];
    const float* user_dense = (const float*)d_in[4];
    const float* item_dense = (const float*)d_in[5];
    const int*   hist_seq   = (const int*)d_in[6];
    const float* user_W     = (const float*)d_in[7];
    const float* item_W     = (const float*)d_in[8];
    const float* cat_W      = (const float*)d_in[9];
    const float* dur_W      = (const float*)d_in[10];
    const float* hist_W     = (const float*)d_in[11];
    const float* aW0 = (const float*)d_in[12];
    const float* ab0 = (const float*)d_in[13];
    const float* aW1 = (const float*)d_in[14];
    const float* ab1 = (const float*)d_in[15];
    const float* aW2 = (const float*)d_in[16];
    const float* ab2 = (const float*)d_in[17];
    const float* mW0 = (const float*)d_in[18];
    const float* mb0 = (const float*)d_in[19];
    const float* mW1 = (const float*)d_in[20];
    const float* mb1 = (const float*)d_in[21];
    const float* mW2 = (const float*)d_in[22];
    const float* mb2 = (const float*)d_in[23];
    float* out = (float*)d_out;
    float* pooled_ws = (float*)d_ws;   // 4096*64 floats = 1 MB (R0 shape)

    attn_kernel<<<4096, 256, 0, stream>>>(item_id, hist_seq, item_W, hist_W,
                                          aW0, ab0, aW1, ab1, aW2, ab2,
                                          pooled_ws);
    mlp_kernel<<<4096 / RB, 256, 0, stream>>>(user_id, item_id, item_cat, item_dur,
                                              user_dense, item_dense,
                                              user_W, item_W, cat_W, dur_W,
                                              mW0, mb0, mW1, mb1, mW2, mb2,
                                              pooled_ws, out);
}

// Round 7
// 392.011 us; speedup vs baseline: 1.3574x; 1.0048x over previous
//
#include <hip/hip_runtime.h>

#define L_SZ 200
#define RB 8
#define HS_STRIDE 72   // bf16 elems per H row: 64 + 8 pad (144 B, 16B-aligned)

typedef __attribute__((ext_vector_type(8))) short short8;   // 8 bf16 = 4 VGPRs (MFMA A/B frag)
typedef __attribute__((ext_vector_type(4))) float floatx4;  // MFMA C/D frag

__device__ __forceinline__ float bf2f(unsigned short h) {
    return __uint_as_float(((unsigned int)h) << 16);
}
// HW packed convert: 1 instruction, RNE. low16 = bf16(a), high16 = bf16(b).
__device__ __forceinline__ unsigned int pk2(float a, float b) {
    unsigned int r;
    asm("v_cvt_pk_bf16_f32 %0, %1, %2" : "=v"(r) : "v"(a), "v"(b));
    return r;
}
__device__ __forceinline__ unsigned short bf1(float a) {
    return (unsigned short)(pk2(a, a) & 0xffffu);
}
__device__ __forceinline__ float wave_sum64(float v) {
    #pragma unroll
    for (int m = 1; m <= 32; m <<= 1) v += __shfl_xor(v, m, 64);
    return v;
}
__device__ __forceinline__ float wave_max64(float v) {
    #pragma unroll
    for (int m = 1; m <= 32; m <<= 1) v = fmaxf(v, __shfl_xor(v, m, 64));
    return v;
}
// LDS-only barrier: waits LDS ops but does NOT drain vmcnt -> early-issued
// global loads stay in flight across it. All intra-block comms are via LDS.
__device__ __forceinline__ void bar_lds() {
    asm volatile("s_waitcnt lgkmcnt(0)" ::: "memory");
    __builtin_amdgcn_s_barrier();
    asm volatile("" ::: "memory");
}

// ---------------------------------------------------------------------------
// attn_kernel: one block per batch element, 256 thr = 4 waves. Self-contained.
// R6 regression root-caused: WeT b16 writes at group (k8g ^ (j&7)) had all 4
// jq-groups sharing j&7 and j*64 ≡ 0 mod 32 banks -> 8 banks for the whole
// wave = 8-way conflict (SQ_LDS_BANK_CONFLICT 426K -> 2.06M). FIX: fold j>>3
// into the XOR group (write AND read). Per unroll step the 4 jq groups now
// get distinct masks {0,2,4,6}+const -> 64 lanes cover all 64 swizzle slots
// exactly once -> 2 lanes/bank (free). Read-side bank profile unchanged.
// ---------------------------------------------------------------------------
__global__ __launch_bounds__(256, 4) void attn_kernel(
    const int* __restrict__ item_id, const int* __restrict__ hist_seq,
    const float* __restrict__ item_W, const float* __restrict__ hist_W,
    const float* __restrict__ aW0, const float* __restrict__ ab0,
    const float* __restrict__ aW1, const float* __restrict__ ab1,
    const float* __restrict__ aW2, const float* __restrict__ ab2,
    float* __restrict__ pooled_ws)
{
    __shared__ __align__(16) unsigned char smem[39648];
    unsigned short* Hs  = (unsigned short*)(smem);           // 200 x 72 bf16 = 28800 B
    unsigned short* BB  = (unsigned short*)(smem + 28800);   // 8192 B: WeT -> scr -> pools
    int*   seq_sh = (int*)(smem + 36992);                    // 200 i32
    float* scores = (float*)(smem + 37792);                  // 200 f32
    float* red    = (float*)(smem + 38592);                  // 8 f32
    float* cbp    = (float*)(smem + 38624);                  // 4 x 64 f32 wave partials

    const int tid  = threadIdx.x;
    const int w    = tid >> 6;
    const int lane = tid & 63;
    const int b    = blockIdx.x;
    const int* hseq = hist_seq + b * L_SZ;

    // stage seq for mask use later
    if (tid < L_SZ) seq_sh[tid] = hseq[tid];

    // ---- deep gather: rows rbase+32t (t<6), plus rows 192..199 for tid<64 ----
    const int rbase = tid >> 3, c8 = tid & 7;
    const bool extra = tid < 64;
    const int r6 = extra ? 192 + rbase : 0;
    const float* sp[7];
    #pragma unroll
    for (int t = 0; t < 6; ++t)
        sp[t] = hist_W + (size_t)hseq[rbase + t * 32] * 64 + c8 * 8;
    sp[6] = hist_W + (size_t)hseq[r6] * 64 + c8 * 8;
    float4 f0[7], f1[7];
    #pragma unroll
    for (int t = 0; t < 7; ++t) {
        f0[t] = *(const float4*)sp[t];
        f1[t] = *(const float4*)(sp[t] + 4);
    }

    // ---- batch-invariant loads issued while the gather is in flight ----
    const int c = lane & 15, q = lane >> 4;
    short8 bW1[2][2];
    #pragma unroll
    for (int nt = 0; nt < 2; ++nt)
        #pragma unroll
        for (int ks = 0; ks < 2; ++ks) {
            float v[8];
            #pragma unroll
            for (int i = 0; i < 8; ++i)
                v[i] = aW1[(ks * 32 + q * 8 + i) * 32 + nt * 16 + c];
            uint4 uu;
            uu.x = pk2(v[0], v[1]); uu.y = pk2(v[2], v[3]);
            uu.z = pk2(v[4], v[5]); uu.w = pk2(v[6], v[7]);
            short8 r; *(uint4*)&r = uu;
            bW1[nt][ks] = r;
        }
    float ab0r[4];
    #pragma unroll
    for (int nt = 0; nt < 4; ++nt) ab0r[nt] = ab0[nt * 16 + c];
    float ab1r[2], aw2r[2];
    #pragma unroll
    for (int nt = 0; nt < 2; ++nt) {
        ab1r[nt] = ab1[nt * 16 + c];
        aw2r[nt] = aW2[nt * 16 + c];
    }
    const float ab2s = ab2[0];

    // ---- pack gather -> Hs (frees the 56 gather VGPRs) ----
    #pragma unroll
    for (int t = 0; t < 6; ++t) {
        uint4 pk;
        pk.x = pk2(f0[t].x, f0[t].y); pk.y = pk2(f0[t].z, f0[t].w);
        pk.z = pk2(f1[t].x, f1[t].y); pk.w = pk2(f1[t].z, f1[t].w);
        *(uint4*)(Hs + (rbase + t * 32) * HS_STRIDE + c8 * 8) = pk;
    }
    if (extra) {
        uint4 pk;
        pk.x = pk2(f0[6].x, f0[6].y); pk.y = pk2(f0[6].z, f0[6].w);
        pk.z = pk2(f1[6].x, f1[6].y); pk.w = pk2(f1[6].z, f1[6].w);
        *(uint4*)(Hs + r6 * HS_STRIDE + c8 * 8) = pk;
    }

    // ---- WeT + cb build: thread (kk, jq) owns k=kk, j in [jq*16, jq*16+16) ----
    // WeT[j][k] = aW0[k][j] + aW0[192+k][j] + ie[k]*aW0[128+k][j]  (bf16, swizzled)
    // storage group g = (k8 ^ (j&7) ^ (j>>3)) & 7   <- j>>3 term kills the
    // 8-way write conflict (R6 fix); reads use the matching XOR below.
    // cb[j]     = ab0[j] + sum_k ie[k]*(aW0[64+k][j] - aW0[192+k][j])
    {
        const int kk = tid >> 2;     // 0..63
        const int jq = tid & 3;      // j-quarter
        const float ie_k = item_W[(size_t)item_id[b] * 64 + kk];
        const float4* a0p = (const float4*)(aW0 + kk * 64 + jq * 16);
        const float4* a1p = (const float4*)(aW0 + (64 + kk) * 64 + jq * 16);
        const float4* a2p = (const float4*)(aW0 + (128 + kk) * 64 + jq * 16);
        const float4* a3p = (const float4*)(aW0 + (192 + kk) * 64 + jq * 16);
        float4 A0[4], A1[4], A2[4], A3[4];
        #pragma unroll
        for (int t = 0; t < 4; ++t) {
            A0[t] = a0p[t]; A1[t] = a1p[t]; A2[t] = a2p[t]; A3[t] = a3p[t];
        }
        const int k8g = kk >> 3, k7 = kk & 7;
        float cbv[16];
        #pragma unroll
        for (int t = 0; t < 4; ++t) {
            const float* p0 = (const float*)&A0[t];
            const float* p1 = (const float*)&A1[t];
            const float* p2 = (const float*)&A2[t];
            const float* p3 = (const float*)&A3[t];
            #pragma unroll
            for (int u = 0; u < 4; ++u) {
                int j = jq * 16 + t * 4 + u;
                float we = p0[u] + p3[u] + ie_k * p2[u];
                int g = (k8g ^ (j & 7) ^ (j >> 3)) & 7;
                BB[j * 64 + (g << 3) + k7] = bf1(we);
                cbv[t * 4 + u] = ie_k * (p1[u] - p3[u]);
            }
        }
        // k-reduce within wave: lanes stride-4 share (jq, j); kk spans w*16..+16
        #pragma unroll
        for (int t = 0; t < 16; ++t) {
            float p = cbv[t];
            p += __shfl_xor(p, 4, 64);
            p += __shfl_xor(p, 8, 64);
            p += __shfl_xor(p, 16, 64);
            p += __shfl_xor(p, 32, 64);
            cbv[t] = p;
        }
        if ((lane >> 2) == 0) {
            #pragma unroll
            for (int t = 0; t < 16; ++t)
                cbp[w * 64 + jq * 16 + t] = cbv[t];
        }
    }
    bar_lds();   // #1: Hs + WeT + cbp visible

    // ---- hoist bW frags from swizzled WeT; finalize cb ----
    // logical k-group kg=4ks+q at j=nt*16+c lives at storage group
    // kg ^ (j&7) ^ (j>>3) = kg ^ (c&7) ^ (nt*2 + (c>>3))
    short8 bW[4][2];
    #pragma unroll
    for (int nt = 0; nt < 4; ++nt)
        #pragma unroll
        for (int ks = 0; ks < 2; ++ks)
            bW[nt][ks] = *(const short8*)(BB + (nt * 16 + c) * 64
                            + ((((4 * ks + q) ^ (c & 7) ^ (nt * 2 + (c >> 3))) & 7) * 8));
    float cbr[4];
    #pragma unroll
    for (int nt = 0; nt < 4; ++nt) {
        int j = nt * 16 + c;
        cbr[nt] = ab0r[nt] + ((cbp[j] + cbp[64 + j]) + (cbp[128 + j] + cbp[192 + j]));
    }
    bar_lds();   // #2: BB free for scr

    unsigned short* scrw = BB + w * (16 * 64);
    const floatx4 zf = {0.f, 0.f, 0.f, 0.f};

    // ---- main: per M-tile  layer0 MFMA -> relu -> scr -> layer1 MFMA -> score ----
    // (tile 12 rows 200..207 read garbage beyond Hs -> rows are independent, masked)
    for (int mt = w; mt < 13; mt += 4) {
        const int rowbase = mt * 16;
        floatx4 acc0[4] = {zf, zf, zf, zf};
        #pragma unroll
        for (int ks = 0; ks < 2; ++ks) {
            short8 a = *(const short8*)(Hs + (rowbase + c) * HS_STRIDE + ks * 32 + q * 8);
            acc0[0] = __builtin_amdgcn_mfma_f32_16x16x32_bf16(a, bW[0][ks], acc0[0], 0, 0, 0);
            acc0[1] = __builtin_amdgcn_mfma_f32_16x16x32_bf16(a, bW[1][ks], acc0[1], 0, 0, 0);
            acc0[2] = __builtin_amdgcn_mfma_f32_16x16x32_bf16(a, bW[2][ks], acc0[2], 0, 0, 0);
            acc0[3] = __builtin_amdgcn_mfma_f32_16x16x32_bf16(a, bW[3][ks], acc0[3], 0, 0, 0);
        }
        // epilogue: +cb, relu, bf16 via cvt_pk pairs (rows r,r+1 share a cvt)
        #pragma unroll
        for (int nt = 0; nt < 4; ++nt)
            #pragma unroll
            for (int r = 0; r < 4; r += 2) {
                float h0 = fmaxf(acc0[nt][r]     + cbr[nt], 0.f);
                float h1 = fmaxf(acc0[nt][r + 1] + cbr[nt], 0.f);
                unsigned int u = pk2(h0, h1);
                int row0 = q * 4 + r;
                int row1 = row0 + 1;
                int gp0 = (2 * nt + (c >> 3)) ^ (row0 & 7);
                int gp1 = (2 * nt + (c >> 3)) ^ (row1 & 7);
                scrw[row0 * 64 + gp0 * 8 + (c & 7)] = (unsigned short)u;
                scrw[row1 * 64 + gp1 * 8 + (c & 7)] = (unsigned short)(u >> 16);
            }
        floatx4 acc1[2] = {zf, zf};
        #pragma unroll
        for (int ks = 0; ks < 2; ++ks) {
            short8 a1 = *(const short8*)(scrw + c * 64 + ((4 * ks + q) ^ (c & 7)) * 8);
            acc1[0] = __builtin_amdgcn_mfma_f32_16x16x32_bf16(a1, bW1[0][ks], acc1[0], 0, 0, 0);
            acc1[1] = __builtin_amdgcn_mfma_f32_16x16x32_bf16(a1, bW1[1][ks], acc1[1], 0, 0, 0);
        }
        // layer2: relu -> *aW2 -> reduce over the 16 col-lanes
        float s[4];
        #pragma unroll
        for (int r = 0; r < 4; ++r)
            s[r] = fmaxf(acc1[0][r] + ab1r[0], 0.f) * aw2r[0]
                 + fmaxf(acc1[1][r] + ab1r[1], 0.f) * aw2r[1];
        #pragma unroll
        for (int m = 1; m <= 8; m <<= 1)
            #pragma unroll
            for (int r = 0; r < 4; ++r) s[r] += __shfl_xor(s[r], m, 64);
        if (c == 0) {
            #pragma unroll
            for (int r = 0; r < 4; ++r) {
                int l = rowbase + q * 4 + r;
                if (l < L_SZ)
                    scores[l] = (seq_sh[l] == 0) ? -1.0e9f : (s[r] + ab2s);
            }
        }
    }
    bar_lds();

    // ---- masked softmax over 200 scores ----
    float s0 = (tid < L_SZ) ? scores[tid] : -3.0e38f;
    float mx = wave_max64(s0);
    if (lane == 0) red[w] = mx;
    bar_lds();
    mx = fmaxf(fmaxf(red[0], red[1]), fmaxf(red[2], red[3]));
    float e = (tid < L_SZ) ? __expf(s0 - mx) : 0.f;
    float sm = wave_sum64(e);
    if (lane == 0) red[4 + w] = sm;
    bar_lds();
    const float winv = 1.f / ((red[4] + red[5]) + (red[6] + red[7]));
    if (tid < L_SZ) scores[tid] = e * winv;
    bar_lds();

    // ---- pooled[j] = sum_l w_l * H[l][j]; 8 row-groups x (2 cols / lane) ----
    float* pools = (float*)BB;   // scr dead now
    {
        int g  = (w << 1) | (lane >> 5);
        int jj = lane & 31;
        int l0 = g * 26, l1 = (l0 + 26 < L_SZ) ? l0 + 26 : L_SZ;
        float p0 = 0.f, p1 = 0.f;
        for (int l = l0; l < l1; ++l) {
            float wt = scores[l];
            unsigned int pv = *(const unsigned int*)(Hs + l * HS_STRIDE + jj * 2);
            p0 = fmaf(wt, bf2f((unsigned short)(pv & 0xffffu)), p0);
            p1 = fmaf(wt, bf2f((unsigned short)(pv >> 16)), p1);
        }
        float2 pp = {p0, p1};
        *(float2*)&pools[g * 64 + jj * 2] = pp;
    }
    bar_lds();
    if (tid < 64) {
        float sum = 0.f;
        #pragma unroll
        for (int g = 0; g < 8; ++g) sum += pools[g * 64 + tid];
        pooled_ws[(size_t)b * 64 + tid] = sum;
    }
}

// Main MLP: 244 -> 256 -> 128 -> 1 -> sigmoid. One block per RB=8 rows.
__global__ __launch_bounds__(256) void mlp_kernel(
    const int* __restrict__ user_id, const int* __restrict__ item_id,
    const int* __restrict__ item_cat, const int* __restrict__ item_dur,
    const float* __restrict__ user_dense, const float* __restrict__ item_dense,
    const float* __restrict__ user_W, const float* __restrict__ item_W,
    const float* __restrict__ cat_W, const float* __restrict__ dur_W,
    const float* __restrict__ mW0, const float* __restrict__ mb0,
    const float* __restrict__ mW1, const float* __restrict__ mb1,
    const float* __restrict__ mW2, const float* __restrict__ mb2,
    const float* __restrict__ pooled_ws, float* __restrict__ out)
{
    __shared__ __align__(16) float xT[244][RB];
    __shared__ __align__(16) float h0T[256][RB];
    __shared__ __align__(16) float h1T[128][RB];
    __shared__ __align__(16) float part[128][RB];

    const int tid = threadIdx.x;
    const int b0 = blockIdx.x * RB;

    for (int idx = tid; idx < 244 * RB; idx += 256) {
        int r = idx / 244;
        int c = idx - r * 244;
        int b = b0 + r;
        float v;
        if (c < 64)       v = user_W[(size_t)user_id[b] * 64 + c];
        else if (c < 128) v = item_W[(size_t)item_id[b] * 64 + (c - 64)];
        else if (c < 144) v = cat_W[item_cat[b] * 16 + (c - 128)];
        else if (c < 152) v = dur_W[item_dur[b] * 8 + (c - 144)];
        else if (c < 177) v = user_dense[b * 25 + (c - 152)];
        else if (c < 180) v = item_dense[b * 3 + (c - 177)];
        else              v = pooled_ws[(size_t)b * 64 + (c - 180)];
        xT[c][r] = v;
    }
    __syncthreads();

    {
        float acc[RB];
        const float bias = mb0[tid];
        #pragma unroll
        for (int r = 0; r < RB; ++r) acc[r] = bias;
        #pragma unroll 4
        for (int k = 0; k < 244; ++k) {
            float wk = mW0[k * 256 + tid];
            float4 xa = *(const float4*)&xT[k][0];
            float4 xb = *(const float4*)&xT[k][4];
            acc[0] = fmaf(wk, xa.x, acc[0]);
            acc[1] = fmaf(wk, xa.y, acc[1]);
            acc[2] = fmaf(wk, xa.z, acc[2]);
            acc[3] = fmaf(wk, xa.w, acc[3]);
            acc[4] = fmaf(wk, xb.x, acc[4]);
            acc[5] = fmaf(wk, xb.y, acc[5]);
            acc[6] = fmaf(wk, xb.z, acc[6]);
            acc[7] = fmaf(wk, xb.w, acc[7]);
        }
        #pragma unroll
        for (int r = 0; r < RB; ++r) h0T[tid][r] = fmaxf(acc[r], 0.f);
    }
    __syncthreads();

    const int jj = tid & 127;
    const int half = tid >> 7;
    {
        float acc[RB];
        #pragma unroll
        for (int r = 0; r < RB; ++r) acc[r] = 0.f;
        #pragma unroll 4
        for (int t = 0; t < 128; ++t) {
            int k = half * 128 + t;
            float wk = mW1[k * 128 + jj];
            float4 ha = *(const float4*)&h0T[k][0];
            float4 hb = *(const float4*)&h0T[k][4];
            acc[0] = fmaf(wk, ha.x, acc[0]);
            acc[1] = fmaf(wk, ha.y, acc[1]);
            acc[2] = fmaf(wk, ha.z, acc[2]);
            acc[3] = fmaf(wk, ha.w, acc[3]);
            acc[4] = fmaf(wk, hb.x, acc[4]);
            acc[5] = fmaf(wk, hb.y, acc[5]);
            acc[6] = fmaf(wk, hb.z, acc[6]);
            acc[7] = fmaf(wk, hb.w, acc[7]);
        }
        if (half == 1) {
            #pragma unroll
            for (int r = 0; r < RB; ++r) part[jj][r] = acc[r];
        }
        __syncthreads();
        if (half == 0) {
            const float bias = mb1[jj];
            #pragma unroll
            for (int r = 0; r < RB; ++r)
                h1T[jj][r] = fmaxf(acc[r] + part[jj][r] + bias, 0.f);
        }
    }
    __syncthreads();

    if (tid < RB) {
        const int r = tid;
        float a0 = mb2[0], a1 = 0.f;
        #pragma unroll 8
        for (int k = 0; k < 128; k += 2) {
            a0 = fmaf(h1T[k][r],     mW2[k],     a0);
            a1 = fmaf(h1T[k + 1][r], mW2[k + 1], a1);
        }
        float a = a0 + a1;
        out[b0 + r] = 1.f / (1.f + __expf(-a));
    }
}

extern "C" void kernel_launch(void* const* d_in, const int* in_sizes, int n_in,
                              void* d_out, int out_size, void* d_ws, size_t ws_size,
                              hipStream_t stream) {
    (void)in_sizes; (void)n_in; (void)out_size; (void)ws_size;
    const int*   user_id    = (const int*)d_in[0];
    const int*   item_id    = (const int*)d_in[1];
    const int*   item_cat   = (const int*)d_in[2];
    const int*   item_dur   = (const int*)d_in[3];
    const float* user_dense = (const float*)d_in[4];
    const float* item_dense = (const float*)d_in[5];
    const int*   hist_seq   = (const int*)d_in[6];
    const float* user_W     = (const float*)d_in[7];
    const float* item_W     = (const float*)d_in[8];
    const float* cat_W      = (const float*)d_in[9];
    const float* dur_W      = (const float*)d_in[10];
    const float* hist_W     = (const float*)d_in[11];
    const float* aW0 = (const float*)d_in[12];
    const float* ab0 = (const float*)d_in[13];
    const float* aW1 = (const float*)d_in[14];
    const float* ab1 = (const float*)d_in[15];
    const float* aW2 = (const float*)d_in[16];
    const float* ab2 = (const float*)d_in[17];
    const float* mW0 = (const float*)d_in[18];
    const float* mb0 = (const float*)d_in[19];
    const float* mW1 = (const float*)d_in[20];
    const float* mb1 = (const float*)d_in[21];
    const float* mW2 = (const float*)d_in[22];
    const float* mb2 = (const float*)d_in[23];
    float* out = (float*)d_out;
    float* pooled_ws = (float*)d_ws;   // 4096*64 floats = 1 MB

    attn_kernel<<<4096, 256, 0, stream>>>(item_id, hist_seq, item_W, hist_W,
                                          aW0, ab0, aW1, ab1, aW2, ab2,
                                          pooled_ws);
    mlp_kernel<<<4096 / RB, 256, 0, stream>>>(user_id, item_id, item_cat, item_dur,
                                              user_dense, item_dense,
                                              user_W, item_W, cat_W, dur_W,
                                              mW0, mb0, mW1, mb1, mW2, mb2,
                                              pooled_ws, out);
}

// Round 8
// 385.168 us; speedup vs baseline: 1.3815x; 1.0178x over previous
//
#include <hip/hip_runtime.h>

#define L_SZ 200
#define RB 8
#define HS_STRIDE 72   // bf16 elems per H row: 64 + 8 pad (144 B, 16B-aligned)

typedef __attribute__((ext_vector_type(8))) short short8;   // 8 bf16 = 4 VGPRs (MFMA A/B frag)
typedef __attribute__((ext_vector_type(4))) float floatx4;  // MFMA C/D frag

__device__ __forceinline__ unsigned short f2bf(float f) {
    unsigned int u = __float_as_uint(f);
    unsigned int r = (u + 0x7fffu + ((u >> 16) & 1u)) >> 16;
    return (unsigned short)r;
}
__device__ __forceinline__ float bf2f(unsigned short h) {
    return __uint_as_float(((unsigned int)h) << 16);
}
// HW packed convert: 1 instruction, RNE (same result as f2bf emulation).
__device__ __forceinline__ unsigned int pk2(float a, float b) {
    unsigned int r;
    asm("v_cvt_pk_bf16_f32 %0, %1, %2" : "=v"(r) : "v"(a), "v"(b));
    return r;   // low16 = bf16(a), high16 = bf16(b)
}
__device__ __forceinline__ float wave_sum64(float v) {
    #pragma unroll
    for (int m = 1; m <= 32; m <<= 1) v += __shfl_xor(v, m, 64);
    return v;
}
__device__ __forceinline__ float wave_max64(float v) {
    #pragma unroll
    for (int m = 1; m <= 32; m <<= 1) v = fmaxf(v, __shfl_xor(v, m, 64));
    return v;
}
// LDS-only barrier: waits LDS ops but does NOT drain vmcnt -> early-issued
// global loads stay in flight across it. All intra-block comms are via LDS.
__device__ __forceinline__ void bar_lds() {
    asm volatile("s_waitcnt lgkmcnt(0)" ::: "memory");
    __builtin_amdgcn_s_barrier();
    asm volatile("" ::: "memory");
}

// ---------------------------------------------------------------------------
// prep_kernel (session-champion config, round-2's 388.7 us run):
//   block 0      : T1t[j][k] = aW0[k][j] + aW0[192+k][j]   (64x64 f32, transposed
//                  via padded LDS, coalesced both sides)
//                  T2t[j][k] = aW0[128+k][j]
//                  PW1 frag-packed bf16 of aW1
//   blocks 1..1024: cb_ws[b][j] = ab0[j] + sum_k iemb_b[k]*(aW0[64+k][j]-aW0[192+k][j])
// ---------------------------------------------------------------------------
__global__ __launch_bounds__(256) void prep_kernel(
    const int* __restrict__ item_id, const float* __restrict__ item_W,
    const float* __restrict__ aW0, const float* __restrict__ ab0,
    const float* __restrict__ aW1,
    float* __restrict__ T1t, float* __restrict__ T2t,
    unsigned short* __restrict__ PW1, float* __restrict__ cb_ws)
{
    __shared__ float shbuf[3 * 64 * 65];   // 49,920 B
    const int tid = threadIdx.x;
    if (blockIdx.x == 0) {
        // coalesced load of aW0 rows {0..63}, {128..191}, {192..255} into LDS
        #pragma unroll
        for (int t = 0; t < 3; ++t) {
            const int r0 = (t == 0) ? 0 : (t == 1) ? 128 : 192;
            for (int u = tid; u < 1024; u += 256) {          // 64 rows x 16 float4
                int k = u >> 4, c4 = u & 15;
                float4 v = *(const float4*)(aW0 + (r0 + k) * 64 + c4 * 4);
                float* dst = shbuf + t * 4160 + k * 65 + c4 * 4;
                dst[0] = v.x; dst[1] = v.y; dst[2] = v.z; dst[3] = v.w;
            }
        }
        __syncthreads();
        // transposed reads from LDS (pad 65 -> banks spread), coalesced writes
        for (int u = tid; u < 4096; u += 256) {
            int j = u >> 6, k = u & 63;
            T1t[u] = shbuf[k * 65 + j] + shbuf[2 * 4160 + k * 65 + j];
            T2t[u] = shbuf[4160 + k * 65 + j];
        }
        for (int u = tid; u < 2048; u += 256) {
            int i = u & 7, lane = (u >> 3) & 63, f = u >> 9;
            int nt = f >> 1, ks = f & 1;
            int k = ks * 32 + (lane >> 4) * 8 + i;
            int n = nt * 16 + (lane & 15);
            PW1[u] = f2bf(aW1[k * 32 + n]);
        }
    } else {
        // stage T3[k][j] (stride 65), reads coalesced (consecutive tid -> j)
        for (int u = tid; u < 4096; u += 256) {
            int k = u >> 6, j = u & 63;
            shbuf[k * 65 + j] = aW0[(64 + k) * 64 + j] - aW0[(192 + k) * 64 + j];
        }
        __syncthreads();
        const int bl = tid >> 6, j = tid & 63;
        const int b = (blockIdx.x - 1) * 4 + bl;
        const float* ie = item_W + (size_t)item_id[b] * 64;
        float acc = ab0[j];
        #pragma unroll 8
        for (int k = 0; k < 64; ++k) acc = fmaf(ie[k], shbuf[k * 65 + j], acc);
        cb_ws[(size_t)b * 64 + j] = acc;
    }
}

// ---------------------------------------------------------------------------
// attn_kernel: one block per batch element. 256 thr = 4 waves. Round-2
// structure (best measured attn at 74.0 us, VGPR 60, no spills) + the two
// verified R5 micro-opts: v_cvt_pk_bf16_f32 packing and LDS-only barriers.
// Deep-issued gather: 14x16B loads in flight/thread before any pack.
// WeT from prepacked T1t/T2t; bW1 from PW1; cb from cb_ws.
// LDS 38,624 B -> 4 blocks/CU.
// ---------------------------------------------------------------------------
__global__ __launch_bounds__(256, 4) void attn_kernel(
    const int* __restrict__ item_id, const int* __restrict__ hist_seq,
    const float* __restrict__ item_W, const float* __restrict__ hist_W,
    const float* __restrict__ T1t, const float* __restrict__ T2t,
    const unsigned short* __restrict__ PW1, const float* __restrict__ cb_ws,
    const float* __restrict__ ab1, const float* __restrict__ aW2,
    const float* __restrict__ ab2, float* __restrict__ pooled_ws)
{
    __shared__ __align__(16) unsigned char smem[38624];
    unsigned short* Hs  = (unsigned short*)(smem);           // 200 x 72 bf16 = 28800 B
    unsigned short* BB  = (unsigned short*)(smem + 28800);   // 8192 B: WeT -> scr -> pools
    int*   seq_sh = (int*)(smem + 36992);                    // 200 i32
    float* scores = (float*)(smem + 37792);                  // 200 f32
    float* red    = (float*)(smem + 38592);                  // 8 f32

    const int tid  = threadIdx.x;
    const int w    = tid >> 6;
    const int lane = tid & 63;
    const int b    = blockIdx.x;
    const int* hseq = hist_seq + b * L_SZ;

    // stage seq for mask use later (independent of gather addressing below)
    if (tid < L_SZ) seq_sh[tid] = hseq[tid];

    // ---- deep gather: rows rbase+32t (t<6), plus rows 192..199 for tid<64 ----
    const int rbase = tid >> 3, c8 = tid & 7;
    const bool extra = tid < 64;
    const int r6 = extra ? 192 + rbase : 0;
    const float* sp[7];
    #pragma unroll
    for (int t = 0; t < 6; ++t)
        sp[t] = hist_W + (size_t)hseq[rbase + t * 32] * 64 + c8 * 8;
    sp[6] = hist_W + (size_t)hseq[r6] * 64 + c8 * 8;
    float4 f0[7], f1[7];
    #pragma unroll
    for (int t = 0; t < 7; ++t) {
        f0[t] = *(const float4*)sp[t];
        f1[t] = *(const float4*)(sp[t] + 4);
    }

    // ---- issue batch-invariant loads while the gather is in flight ----
    const int c = lane & 15, q = lane >> 4;
    short8 bW1[2][2];
    #pragma unroll
    for (int nt = 0; nt < 2; ++nt)
        #pragma unroll
        for (int ks = 0; ks < 2; ++ks)
            bW1[nt][ks] = *(const short8*)(PW1 + ((nt * 2 + ks) * 64 + lane) * 8);
    float cbr[4];
    #pragma unroll
    for (int nt = 0; nt < 4; ++nt) cbr[nt] = cb_ws[(size_t)b * 64 + nt * 16 + c];
    float ab1r[2], aw2r[2];
    #pragma unroll
    for (int nt = 0; nt < 2; ++nt) {
        ab1r[nt] = ab1[nt * 16 + c];
        aw2r[nt] = aW2[nt * 16 + c];
    }
    const float ab2s = ab2[0];

    // ---- pack gather -> Hs (per-use vmcnt keeps later loads outstanding) ----
    #pragma unroll
    for (int t = 0; t < 6; ++t) {
        uint4 pk;
        pk.x = pk2(f0[t].x, f0[t].y); pk.y = pk2(f0[t].z, f0[t].w);
        pk.z = pk2(f1[t].x, f1[t].y); pk.w = pk2(f1[t].z, f1[t].w);
        *(uint4*)(Hs + (rbase + t * 32) * HS_STRIDE + c8 * 8) = pk;
    }
    if (extra) {
        uint4 pk;
        pk.x = pk2(f0[6].x, f0[6].y); pk.y = pk2(f0[6].z, f0[6].w);
        pk.z = pk2(f1[6].x, f1[6].y); pk.w = pk2(f1[6].z, f1[6].w);
        *(uint4*)(Hs + r6 * HS_STRIDE + c8 * 8) = pk;
    }

    // ---- WeT build from prepacked tables: bf16(T1 + iemb*T2), swizzled ----
    {
        const float* irow = item_W + (size_t)item_id[b] * 64;
        const int j0 = tid >> 3;   // 0..31
        float4 em0 = *(const float4*)(irow + c8 * 8);
        float4 em1 = *(const float4*)(irow + c8 * 8 + 4);
        #pragma unroll
        for (int t = 0; t < 2; ++t) {
            int j = j0 + t * 32;
            const float* p1 = T1t + j * 64 + c8 * 8;
            const float* p2 = T2t + j * 64 + c8 * 8;
            float4 a0 = *(const float4*)p1, a1 = *(const float4*)(p1 + 4);
            float4 b0 = *(const float4*)p2, b1 = *(const float4*)(p2 + 4);
            float v[8];
            v[0] = a0.x + em0.x * b0.x; v[1] = a0.y + em0.y * b0.y;
            v[2] = a0.z + em0.z * b0.z; v[3] = a0.w + em0.w * b0.w;
            v[4] = a1.x + em1.x * b1.x; v[5] = a1.y + em1.y * b1.y;
            v[6] = a1.z + em1.z * b1.z; v[7] = a1.w + em1.w * b1.w;
            uint4 pk;
            pk.x = pk2(v[0], v[1]); pk.y = pk2(v[2], v[3]);
            pk.z = pk2(v[4], v[5]); pk.w = pk2(v[6], v[7]);
            *(uint4*)(BB + j * 64 + (c8 ^ (j & 7)) * 8) = pk;
        }
    }
    bar_lds();   // #1: Hs + WeT visible

    // ---- hoist bW frags from swizzled WeT ----
    short8 bW[4][2];
    #pragma unroll
    for (int nt = 0; nt < 4; ++nt)
        #pragma unroll
        for (int ks = 0; ks < 2; ++ks)
            bW[nt][ks] = *(const short8*)(BB + (nt * 16 + c) * 64
                                             + ((4 * ks + q) ^ (c & 7)) * 8);
    bar_lds();   // #2: BB free for scr

    unsigned short* scrw = BB + w * (16 * 64);
    const floatx4 zf = {0.f, 0.f, 0.f, 0.f};

    // ---- main: per M-tile  layer0 MFMA -> relu -> scr -> layer1 MFMA -> score ----
    // (tile 12 rows 200..207 read garbage beyond Hs -> rows are independent, masked)
    for (int mt = w; mt < 13; mt += 4) {
        const int rowbase = mt * 16;
        floatx4 acc0[4] = {zf, zf, zf, zf};
        #pragma unroll
        for (int ks = 0; ks < 2; ++ks) {
            short8 a = *(const short8*)(Hs + (rowbase + c) * HS_STRIDE + ks * 32 + q * 8);
            acc0[0] = __builtin_amdgcn_mfma_f32_16x16x32_bf16(a, bW[0][ks], acc0[0], 0, 0, 0);
            acc0[1] = __builtin_amdgcn_mfma_f32_16x16x32_bf16(a, bW[1][ks], acc0[1], 0, 0, 0);
            acc0[2] = __builtin_amdgcn_mfma_f32_16x16x32_bf16(a, bW[2][ks], acc0[2], 0, 0, 0);
            acc0[3] = __builtin_amdgcn_mfma_f32_16x16x32_bf16(a, bW[3][ks], acc0[3], 0, 0, 0);
        }
        // epilogue: +cb, relu, bf16 via cvt_pk pairs (rows r,r+1 share a cvt)
        #pragma unroll
        for (int nt = 0; nt < 4; ++nt)
            #pragma unroll
            for (int r = 0; r < 4; r += 2) {
                float h0 = fmaxf(acc0[nt][r]     + cbr[nt], 0.f);
                float h1 = fmaxf(acc0[nt][r + 1] + cbr[nt], 0.f);
                unsigned int u = pk2(h0, h1);
                int row0 = q * 4 + r;
                int row1 = row0 + 1;
                int gp0 = (2 * nt + (c >> 3)) ^ (row0 & 7);
                int gp1 = (2 * nt + (c >> 3)) ^ (row1 & 7);
                scrw[row0 * 64 + gp0 * 8 + (c & 7)] = (unsigned short)u;
                scrw[row1 * 64 + gp1 * 8 + (c & 7)] = (unsigned short)(u >> 16);
            }
        floatx4 acc1[2] = {zf, zf};
        #pragma unroll
        for (int ks = 0; ks < 2; ++ks) {
            short8 a1 = *(const short8*)(scrw + c * 64 + ((4 * ks + q) ^ (c & 7)) * 8);
            acc1[0] = __builtin_amdgcn_mfma_f32_16x16x32_bf16(a1, bW1[0][ks], acc1[0], 0, 0, 0);
            acc1[1] = __builtin_amdgcn_mfma_f32_16x16x32_bf16(a1, bW1[1][ks], acc1[1], 0, 0, 0);
        }
        // layer2: relu -> *aW2 -> reduce over the 16 col-lanes
        float s[4];
        #pragma unroll
        for (int r = 0; r < 4; ++r)
            s[r] = fmaxf(acc1[0][r] + ab1r[0], 0.f) * aw2r[0]
                 + fmaxf(acc1[1][r] + ab1r[1], 0.f) * aw2r[1];
        #pragma unroll
        for (int m = 1; m <= 8; m <<= 1)
            #pragma unroll
            for (int r = 0; r < 4; ++r) s[r] += __shfl_xor(s[r], m, 64);
        if (c == 0) {
            #pragma unroll
            for (int r = 0; r < 4; ++r) {
                int l = rowbase + q * 4 + r;
                if (l < L_SZ)
                    scores[l] = (seq_sh[l] == 0) ? -1.0e9f : (s[r] + ab2s);
            }
        }
    }
    bar_lds();

    // ---- masked softmax over 200 scores ----
    float s0 = (tid < L_SZ) ? scores[tid] : -3.0e38f;
    float mx = wave_max64(s0);
    if (lane == 0) red[w] = mx;
    bar_lds();
    mx = fmaxf(fmaxf(red[0], red[1]), fmaxf(red[2], red[3]));
    float e = (tid < L_SZ) ? __expf(s0 - mx) : 0.f;
    float sm = wave_sum64(e);
    if (lane == 0) red[4 + w] = sm;
    bar_lds();
    const float winv = 1.f / ((red[4] + red[5]) + (red[6] + red[7]));
    if (tid < L_SZ) scores[tid] = e * winv;
    bar_lds();

    // ---- pooled[j] = sum_l w_l * H[l][j]; 8 row-groups x (2 cols / lane) ----
    float* pools = (float*)BB;   // scr dead now
    {
        int g  = (w << 1) | (lane >> 5);
        int jj = lane & 31;
        int l0 = g * 26, l1 = (l0 + 26 < L_SZ) ? l0 + 26 : L_SZ;
        float p0 = 0.f, p1 = 0.f;
        for (int l = l0; l < l1; ++l) {
            float wt = scores[l];
            unsigned int pv = *(const unsigned int*)(Hs + l * HS_STRIDE + jj * 2);
            p0 = fmaf(wt, bf2f((unsigned short)(pv & 0xffffu)), p0);
            p1 = fmaf(wt, bf2f((unsigned short)(pv >> 16)), p1);
        }
        float2 pp = {p0, p1};
        *(float2*)&pools[g * 64 + jj * 2] = pp;
    }
    bar_lds();
    if (tid < 64) {
        float sum = 0.f;
        #pragma unroll
        for (int g = 0; g < 8; ++g) sum += pools[g * 64 + tid];
        pooled_ws[(size_t)b * 64 + tid] = sum;
    }
}

// Main MLP: 244 -> 256 -> 128 -> 1 -> sigmoid. One block per RB=8 rows.
__global__ __launch_bounds__(256) void mlp_kernel(
    const int* __restrict__ user_id, const int* __restrict__ item_id,
    const int* __restrict__ item_cat, const int* __restrict__ item_dur,
    const float* __restrict__ user_dense, const float* __restrict__ item_dense,
    const float* __restrict__ user_W, const float* __restrict__ item_W,
    const float* __restrict__ cat_W, const float* __restrict__ dur_W,
    const float* __restrict__ mW0, const float* __restrict__ mb0,
    const float* __restrict__ mW1, const float* __restrict__ mb1,
    const float* __restrict__ mW2, const float* __restrict__ mb2,
    const float* __restrict__ pooled_ws, float* __restrict__ out)
{
    __shared__ __align__(16) float xT[244][RB];
    __shared__ __align__(16) float h0T[256][RB];
    __shared__ __align__(16) float h1T[128][RB];
    __shared__ __align__(16) float part[128][RB];

    const int tid = threadIdx.x;
    const int b0 = blockIdx.x * RB;

    for (int idx = tid; idx < 244 * RB; idx += 256) {
        int r = idx / 244;
        int c = idx - r * 244;
        int b = b0 + r;
        float v;
        if (c < 64)       v = user_W[(size_t)user_id[b] * 64 + c];
        else if (c < 128) v = item_W[(size_t)item_id[b] * 64 + (c - 64)];
        else if (c < 144) v = cat_W[item_cat[b] * 16 + (c - 128)];
        else if (c < 152) v = dur_W[item_dur[b] * 8 + (c - 144)];
        else if (c < 177) v = user_dense[b * 25 + (c - 152)];
        else if (c < 180) v = item_dense[b * 3 + (c - 177)];
        else              v = pooled_ws[(size_t)b * 64 + (c - 180)];
        xT[c][r] = v;
    }
    __syncthreads();

    {
        float acc[RB];
        const float bias = mb0[tid];
        #pragma unroll
        for (int r = 0; r < RB; ++r) acc[r] = bias;
        #pragma unroll 4
        for (int k = 0; k < 244; ++k) {
            float wk = mW0[k * 256 + tid];
            float4 xa = *(const float4*)&xT[k][0];
            float4 xb = *(const float4*)&xT[k][4];
            acc[0] = fmaf(wk, xa.x, acc[0]);
            acc[1] = fmaf(wk, xa.y, acc[1]);
            acc[2] = fmaf(wk, xa.z, acc[2]);
            acc[3] = fmaf(wk, xa.w, acc[3]);
            acc[4] = fmaf(wk, xb.x, acc[4]);
            acc[5] = fmaf(wk, xb.y, acc[5]);
            acc[6] = fmaf(wk, xb.z, acc[6]);
            acc[7] = fmaf(wk, xb.w, acc[7]);
        }
        #pragma unroll
        for (int r = 0; r < RB; ++r) h0T[tid][r] = fmaxf(acc[r], 0.f);
    }
    __syncthreads();

    const int jj = tid & 127;
    const int half = tid >> 7;
    {
        float acc[RB];
        #pragma unroll
        for (int r = 0; r < RB; ++r) acc[r] = 0.f;
        #pragma unroll 4
        for (int t = 0; t < 128; ++t) {
            int k = half * 128 + t;
            float wk = mW1[k * 128 + jj];
            float4 ha = *(const float4*)&h0T[k][0];
            float4 hb = *(const float4*)&h0T[k][4];
            acc[0] = fmaf(wk, ha.x, acc[0]);
            acc[1] = fmaf(wk, ha.y, acc[1]);
            acc[2] = fmaf(wk, ha.z, acc[2]);
            acc[3] = fmaf(wk, ha.w, acc[3]);
            acc[4] = fmaf(wk, hb.x, acc[4]);
            acc[5] = fmaf(wk, hb.y, acc[5]);
            acc[6] = fmaf(wk, hb.z, acc[6]);
            acc[7] = fmaf(wk, hb.w, acc[7]);
        }
        if (half == 1) {
            #pragma unroll
            for (int r = 0; r < RB; ++r) part[jj][r] = acc[r];
        }
        __syncthreads();
        if (half == 0) {
            const float bias = mb1[jj];
            #pragma unroll
            for (int r = 0; r < RB; ++r)
                h1T[jj][r] = fmaxf(acc[r] + part[jj][r] + bias, 0.f);
        }
    }
    __syncthreads();

    if (tid < RB) {
        const int r = tid;
        float a0 = mb2[0], a1 = 0.f;
        #pragma unroll 8
        for (int k = 0; k < 128; k += 2) {
            a0 = fmaf(h1T[k][r],     mW2[k],     a0);
            a1 = fmaf(h1T[k + 1][r], mW2[k + 1], a1);
        }
        float a = a0 + a1;
        out[b0 + r] = 1.f / (1.f + __expf(-a));
    }
}

extern "C" void kernel_launch(void* const* d_in, const int* in_sizes, int n_in,
                              void* d_out, int out_size, void* d_ws, size_t ws_size,
                              hipStream_t stream) {
    (void)in_sizes; (void)n_in; (void)out_size; (void)ws_size;
    const int*   user_id    = (const int*)d_in[0];
    const int*   item_id    = (const int*)d_in[1];
    const int*   item_cat   = (const int*)d_in[2];
    const int*   item_dur   = (const int*)d_in[3];
    const float* user_dense = (const float*)d_in[4];
    const float* item_dense = (const float*)d_in[5];
    const int*   hist_seq   = (const int*)d_in[6];
    const float* user_W     = (const float*)d_in[7];
    const float* item_W     = (const float*)d_in[8];
    const float* cat_W      = (const float*)d_in[9];
    const float* dur_W      = (const float*)d_in[10];
    const float* hist_W     = (const float*)d_in[11];
    const float* aW0 = (const float*)d_in[12];
    const float* ab0 = (const float*)d_in[13];
    const float* aW1 = (const float*)d_in[14];
    const float* ab1 = (const float*)d_in[15];
    const float* aW2 = (const float*)d_in[16];
    const float* ab2 = (const float*)d_in[17];
    const float* mW0 = (const float*)d_in[18];
    const float* mb0 = (const float*)d_in[19];
    const float* mW1 = (const float*)d_in[20];
    const float* mb1 = (const float*)d_in[21];
    const float* mW2 = (const float*)d_in[22];
    const float* mb2 = (const float*)d_in[23];
    float* out = (float*)d_out;

    // workspace layout: pooled 1MB | cb 1MB | T1t 16KB | T2t 16KB | PW1 4KB
    char* ws = (char*)d_ws;
    float* pooled_ws = (float*)ws;                               // 4096*64 f32
    float* cb_ws     = (float*)(ws + (1u << 20));                // 4096*64 f32
    float* T1t       = (float*)(ws + (2u << 20));                // 64*64 f32
    float* T2t       = (float*)(ws + (2u << 20) + 16384);        // 64*64 f32
    unsigned short* PW1 = (unsigned short*)(ws + (2u << 20) + 32768); // 2048 bf16

    prep_kernel<<<1025, 256, 0, stream>>>(item_id, item_W, aW0, ab0, aW1,
                                          T1t, T2t, PW1, cb_ws);
    attn_kernel<<<4096, 256, 0, stream>>>(item_id, hist_seq, item_W, hist_W,
                                          T1t, T2t, PW1, cb_ws,
                                          ab1, aW2, ab2, pooled_ws);
    mlp_kernel<<<4096 / RB, 256, 0, stream>>>(user_id, item_id, item_cat, item_dur,
                                              user_dense, item_dense,
                                              user_W, item_W, cat_W, dur_W,
                                              mW0, mb0, mW1, mb1, mW2, mb2,
                                              pooled_ws, out);
}